// Round 2
// baseline (398.573 us; speedup 1.0000x reference)
//
#include <hip/hip_runtime.h>
#include <stdint.h>

#define L_SEQ 4096
#define D_MODEL 1024
#define HEAD 64

typedef unsigned short u16;
typedef __attribute__((ext_vector_type(8))) short bf16x8;
typedef __attribute__((ext_vector_type(4))) float f32x4;

static __device__ __forceinline__ u16 f2bf(float f) {
    union { float f; uint32_t u; } c; c.f = f;
    uint32_t u = c.u;
    return (u16)((u + 0x7FFFu + ((u >> 16) & 1u)) >> 16);
}

static __device__ __forceinline__ bf16x8 ld8(const u16* p) {
    return *(const bf16x8*)p;
}

// load 8 consecutive fp32, round to bf16x8
static __device__ __forceinline__ bf16x8 cvt8(const float* p) {
    const float4* q = (const float4*)p;
    float4 a = q[0], b = q[1];
    bf16x8 r;
    r[0] = (short)f2bf(a.x); r[1] = (short)f2bf(a.y);
    r[2] = (short)f2bf(a.z); r[3] = (short)f2bf(a.w);
    r[4] = (short)f2bf(b.x); r[5] = (short)f2bf(b.y);
    r[6] = (short)f2bf(b.z); r[7] = (short)f2bf(b.w);
    return r;
}

static __device__ __forceinline__ f32x4 mfma16(bf16x8 a, bf16x8 b, f32x4 c) {
    return __builtin_amdgcn_mfma_f32_16x16x32_bf16(a, b, c, 0, 0, 0);
}

// --- Kernel 0: convert+transpose W fp32 [1024,64] -> bf16 Wt [64,1024] x3
__global__ __launch_bounds__(256) void conv_w(
    const float* __restrict__ Wq, const float* __restrict__ Wk,
    const float* __restrict__ Wv, u16* __restrict__ Wt)
{
    const float* W = (blockIdx.y == 0) ? Wq : (blockIdx.y == 1) ? Wk : Wv;
    u16* dst = Wt + blockIdx.y * (HEAD * D_MODEL);
    int base = blockIdx.x * 2048 + threadIdx.x;
    #pragma unroll
    for (int i = 0; i < 8; i++) {
        int idx = base + i * 256;             // idx = k*64 + h
        int k = idx >> 6, h = idx & 63;
        dst[h * D_MODEL + k] = f2bf(W[idx]);
    }
}

// --- Kernel 1: fused QKV projection. One pass over fp32 x; q,k row-major
// bf16, v transposed [B,64,L] bf16. grid 256, block 256 = 4 waves x 16 rows.
__global__ __launch_bounds__(256) void qkv_proj(
    const float* __restrict__ x, const u16* __restrict__ Wt,
    u16* __restrict__ qb, u16* __restrict__ kb, u16* __restrict__ vTb)
{
    const int tid  = threadIdx.x;
    const int wave = tid >> 6, lane = tid & 63;
    const int ln16 = lane & 15, quad = lane >> 4;
    const int mbase = blockIdx.x * 64 + wave * 16;

    f32x4 acc[3][4] = {};
    const float* arow = x + (size_t)(mbase + ln16) * D_MODEL + quad * 8;
    const u16* brow = Wt + (size_t)ln16 * D_MODEL + quad * 8;
    for (int k0 = 0; k0 < D_MODEL; k0 += 32) {
        bf16x8 a = cvt8(arow + k0);
        #pragma unroll
        for (int w = 0; w < 3; w++) {
            #pragma unroll
            for (int nt = 0; nt < 4; nt++) {
                bf16x8 b = ld8(brow + (w * 64 + nt * 16) * D_MODEL + k0);
                acc[w][nt] = mfma16(a, b, acc[w][nt]);
            }
        }
    }
    // C/D layout: col = lane&15, row = quad*4 + reg  [verified m89/m91]
    #pragma unroll
    for (int nt = 0; nt < 4; nt++) {
        #pragma unroll
        for (int r = 0; r < 4; r++) {
            int m = mbase + quad * 4 + r;
            int h = nt * 16 + ln16;
            qb[(size_t)m * HEAD + h] = f2bf(acc[0][nt][r]);
            kb[(size_t)m * HEAD + h] = f2bf(acc[1][nt][r]);
            int bb = m >> 12, l = m & 4095;   // v stored transposed [B,64,L]
            vTb[(size_t)(bb * HEAD + h) * L_SEQ + l] = f2bf(acc[2][nt][r]);
        }
    }
}

// --- Kernel 2: causal flash attention, fp32 output.
// grid (64 q-tiles, 4 batches), block 256 = 4 waves; wave owns 16 q-rows.
__global__ __launch_bounds__(256) void attn(
    const u16* __restrict__ qb, const u16* __restrict__ kb,
    const u16* __restrict__ vT, float* __restrict__ out)
{
    __shared__ __align__(16) u16 Pbuf[4][16 * 32];  // per-wave P tile
    const int b  = blockIdx.y;
    const int qt = gridDim.x - 1 - blockIdx.x;      // big q-tiles dispatch first
    const int tid  = threadIdx.x;
    const int wave = tid >> 6, lane = tid & 63;
    const int ln16 = lane & 15, quad = lane >> 4;
    const int qbase = qt * 64 + wave * 16;

    // Q A-frags: A[m=lane&15][k=quad*8+j]  [verified m118/m120]
    const u16* qrow = qb + (size_t)(b * L_SEQ + qbase + ln16) * HEAD + quad * 8;
    bf16x8 qa0 = ld8(qrow);
    bf16x8 qa1 = ld8(qrow + 32);

    f32x4 o[4] = {};
    float m_i[4], l_i[4];
    #pragma unroll
    for (int r = 0; r < 4; r++) { m_i[r] = -1e30f; l_i[r] = 0.f; }

    const u16* kbb = kb + (size_t)b * L_SEQ * HEAD;
    const u16* vbb = vT + (size_t)b * HEAD * L_SEQ;
    u16* P = Pbuf[wave];
    const int ntile = 2 * qt + 2;   // block-uniform kv-tile count (32 wide)

    for (int t = 0; t < ntile; t++) {
        const int kv0 = t * 32;
        // S = Q K^T : B-frag B[k=quad*8+j][n=lane&15] = K[kv0+n][k] (contig 16B)
        const u16* krow = kbb + (size_t)(kv0 + ln16) * HEAD + quad * 8;
        f32x4 s0 = {}, s1 = {};
        s0 = mfma16(qa0, ld8(krow), s0);
        s0 = mfma16(qa1, ld8(krow + 32), s0);
        s1 = mfma16(qa0, ld8(krow + 16 * HEAD), s1);
        s1 = mfma16(qa1, ld8(krow + 16 * HEAD + 32), s1);

        // online softmax; S C-layout: row=quad*4+r (same lanes as O rows), col=ln16
        #pragma unroll
        for (int r = 0; r < 4; r++) {
            int qr = qbase + quad * 4 + r;
            float v0 = s0[r] * 0.125f;
            float v1 = s1[r] * 0.125f;
            if (kv0 + ln16 > qr)      v0 = -1e30f;
            if (kv0 + 16 + ln16 > qr) v1 = -1e30f;
            float mx = fmaxf(v0, v1);
            #pragma unroll
            for (int sh = 1; sh < 16; sh <<= 1)
                mx = fmaxf(mx, __shfl_xor(mx, sh));
            float m_new = fmaxf(m_i[r], mx);
            float alpha = __expf(m_i[r] - m_new);
            float p0 = __expf(v0 - m_new);
            float p1 = __expf(v1 - m_new);
            float ps = p0 + p1;
            #pragma unroll
            for (int sh = 1; sh < 16; sh <<= 1)
                ps += __shfl_xor(ps, sh);
            l_i[r] = l_i[r] * alpha + ps;
            m_i[r] = m_new;
            #pragma unroll
            for (int nt = 0; nt < 4; nt++) o[nt][r] *= alpha;
            int prow = quad * 4 + r;
            P[prow * 32 + ln16]      = f2bf(p0);
            P[prow * 32 + 16 + ln16] = f2bf(p1);
        }
        __syncthreads();
        // P re-enters as A-operand: read A[m=ln16][k=quad*8+j] from LDS
        bf16x8 pa = ld8(P + ln16 * 32 + quad * 8);
        // PV B-frag: B[k][n] = vT[h0+n][kv0+k] (contig 16B)
        const u16* vrow = vbb + (size_t)ln16 * L_SEQ + kv0 + quad * 8;
        #pragma unroll
        for (int nt = 0; nt < 4; nt++) {
            o[nt] = mfma16(pa, ld8(vrow + (size_t)(nt * 16) * L_SEQ), o[nt]);
        }
        __syncthreads();
    }

    #pragma unroll
    for (int r = 0; r < 4; r++) {
        int qr = qbase + quad * 4 + r;
        float invl = 1.f / l_i[r];
        #pragma unroll
        for (int nt = 0; nt < 4; nt++) {
            out[(size_t)(b * L_SEQ + qr) * HEAD + nt * 16 + ln16] =
                o[nt][r] * invl;
        }
    }
}

extern "C" void kernel_launch(void* const* d_in, const int* in_sizes, int n_in,
                              void* d_out, int out_size, void* d_ws, size_t ws_size,
                              hipStream_t stream) {
    const float* x  = (const float*)d_in[0];
    const float* Wq = (const float*)d_in[1];
    const float* Wk = (const float*)d_in[2];
    const float* Wv = (const float*)d_in[3];
    float* out = (float*)d_out;
    u16* ws  = (u16*)d_ws;

    u16* Wt  = ws;                          // 3 * 64*1024 elems
    u16* qb  = ws + 3 * HEAD * D_MODEL;     // [4,4096,64]
    u16* kb  = qb + 16384 * HEAD;           // [4,4096,64]
    u16* vTb = kb + 16384 * HEAD;           // [4,64,4096]

    conv_w   <<<dim3(32, 3), 256, 0, stream>>>(Wq, Wk, Wv, Wt);
    qkv_proj <<<dim3(256), 256, 0, stream>>>(x, Wt, qb, kb, vTb);
    attn     <<<dim3(64, 4), 256, 0, stream>>>(qb, kb, vTb, out);
}

// Round 3
// 319.269 us; speedup vs baseline: 1.2484x; 1.2484x over previous
//
#include <hip/hip_runtime.h>
#include <stdint.h>

#define L_SEQ 4096
#define D_MODEL 1024
#define HEAD 64
#define CHUNK 512
#define MAXCH 8

typedef unsigned short u16;
typedef __attribute__((ext_vector_type(8))) short bf16x8;
typedef __attribute__((ext_vector_type(4))) float f32x4;

static __device__ __forceinline__ u16 f2bf(float f) {
    union { float f; uint32_t u; } c; c.f = f;
    uint32_t u = c.u;
    return (u16)((u + 0x7FFFu + ((u >> 16) & 1u)) >> 16);
}
static __device__ __forceinline__ bf16x8 ld8(const u16* p) { return *(const bf16x8*)p; }

static __device__ __forceinline__ bf16x8 cvt8(const float* p) {
    const float4* q = (const float4*)p;
    float4 a = q[0], b = q[1];
    bf16x8 r;
    r[0] = (short)f2bf(a.x); r[1] = (short)f2bf(a.y);
    r[2] = (short)f2bf(a.z); r[3] = (short)f2bf(a.w);
    r[4] = (short)f2bf(b.x); r[5] = (short)f2bf(b.y);
    r[6] = (short)f2bf(b.z); r[7] = (short)f2bf(b.w);
    return r;
}
static __device__ __forceinline__ f32x4 mfma16(bf16x8 a, bf16x8 b, f32x4 c) {
    return __builtin_amdgcn_mfma_f32_16x16x32_bf16(a, b, c, 0, 0, 0);
}

// --- Kernel 0: W fp32 [1024,64] -> bf16 Wt [64,1024] x3, LDS transpose (coalesced both sides)
__global__ __launch_bounds__(256) void conv_w(
    const float* __restrict__ Wq, const float* __restrict__ Wk,
    const float* __restrict__ Wv, u16* __restrict__ Wt)
{
    __shared__ u16 tile[64][72];
    const float* W = (blockIdx.y == 0) ? Wq : (blockIdx.y == 1) ? Wk : Wv;
    u16* dst = Wt + blockIdx.y * (HEAD * D_MODEL);
    const int k0 = blockIdx.x * 64, t = threadIdx.x;
    #pragma unroll
    for (int i = 0; i < 16; i++) {
        int idx = i * 256 + t;          // idx = kk*64 + h
        int kk = idx >> 6, h = idx & 63;
        tile[h][kk] = f2bf(W[(size_t)(k0 + kk) * HEAD + h]);
    }
    __syncthreads();
    #pragma unroll
    for (int i = 0; i < 16; i++) {
        int idx = i * 256 + t;          // idx = h*64 + kk
        int h = idx >> 6, kk = idx & 63;
        dst[(size_t)h * D_MODEL + k0 + kk] = tile[h][kk];
    }
}

// --- Kernel 1: fused QKV projection. 512 blocks; block = 2 m-tiles x 2 K-halves.
__global__ __launch_bounds__(256) void qkv_proj(
    const float* __restrict__ x, const u16* __restrict__ Wt,
    u16* __restrict__ qb, u16* __restrict__ kb, u16* __restrict__ vTb)
{
    __shared__ __align__(16) float accbuf[2][12][64][4];   // 24 KB
    __shared__ __align__(16) u16 vtile[64][40];            // 5 KB, padded rows (80B, 16B mult)
    const int t = threadIdx.x;
    const int wv = t >> 6, lane = t & 63;
    const int ln16 = lane & 15, quad = lane >> 4;
    const int mt = wv & 1, kh = wv >> 1;
    const int mbase = blockIdx.x * 32 + mt * 16;

    f32x4 acc[12] = {};
    const float* arow = x + (size_t)(mbase + ln16) * D_MODEL + kh * 512 + quad * 8;
    const u16* brow = Wt + (size_t)ln16 * D_MODEL + kh * 512 + quad * 8;
    for (int k0 = 0; k0 < 512; k0 += 32) {
        bf16x8 a = cvt8(arow + k0);
        #pragma unroll
        for (int i = 0; i < 12; i++) {                      // col block i*16 (q:0-3, k:4-7, v:8-11)
            bf16x8 b = ld8(brow + (size_t)(i * 16) * D_MODEL + k0);
            acc[i] = mfma16(a, b, acc[i]);
        }
    }
    if (kh == 1) {
        #pragma unroll
        for (int i = 0; i < 12; i++)
            *(f32x4*)&accbuf[mt][i][lane][0] = acc[i];
    }
    __syncthreads();
    if (kh == 0) {
        #pragma unroll
        for (int i = 0; i < 12; i++) {
            f32x4 o = *(f32x4*)&accbuf[mt][i][lane][0];
            acc[i][0] += o[0]; acc[i][1] += o[1]; acc[i][2] += o[2]; acc[i][3] += o[3];
        }
        #pragma unroll
        for (int i = 0; i < 12; i++) {
            int w = i >> 2, nt = i & 3;
            #pragma unroll
            for (int r = 0; r < 4; r++) {
                int m = mbase + quad * 4 + r;    // C/D: col=lane&15, row=quad*4+reg
                int h = nt * 16 + ln16;
                u16 bits = f2bf(acc[i][r]);
                if (w == 0)      qb[(size_t)m * HEAD + h] = bits;
                else if (w == 1) kb[(size_t)m * HEAD + h] = bits;
                else             vtile[h][mt * 16 + quad * 4 + r] = bits;
            }
        }
    }
    __syncthreads();
    {   // cooperative coalesced vT store: 64 h rows x 32 m
        int h = t >> 2, piece = t & 3;
        int mloc = piece * 8;
        bf16x8 v = *(bf16x8*)&vtile[h][mloc];
        int mg = blockIdx.x * 32 + mloc;
        int bb = mg >> 12, l = mg & 4095;
        *(bf16x8*)&vTb[(size_t)(bb * HEAD + h) * L_SEQ + l] = v;
    }
}

// --- Kernel 2: split-KV causal flash attention, transposed-S formulation.
// grid (ch=8, qt=64, b=4), block 256 = 4 waves x 16 q-rows. No barriers.
__global__ __launch_bounds__(256) void attn_chunk(
    const u16* __restrict__ qb, const u16* __restrict__ kb,
    const u16* __restrict__ vT, float* __restrict__ Opart, float* __restrict__ ml)
{
    const int ch = blockIdx.x, qt = blockIdx.y, b = blockIdx.z;
    if (ch * CHUNK > qt * 64 + 63) return;
    const int t = threadIdx.x, wv = t >> 6, lane = t & 63;
    const int ln16 = lane & 15, quad = lane >> 4;
    const int q_local = wv * 16 + ln16;
    const int qrow = qt * 64 + q_local;

    __shared__ __align__(16) u16 Pb[4][16][72];   // per-wave P tile, padded rows (144B)
    u16 (*P)[72] = Pb[wv];

    // Q enters as B-operand: B[k=d=quad*8+j][n=q=ln16]
    const u16* qrp = qb + (size_t)(b * L_SEQ + qrow) * HEAD + quad * 8;
    bf16x8 qf0 = ld8(qrp), qf1 = ld8(qrp + 32);

    const u16* kbb = kb + (size_t)b * L_SEQ * HEAD;
    const u16* vbb = vT + (size_t)b * HEAD * L_SEQ;

    f32x4 o[4] = {};                 // O^T[h=hg*16+quad*4+r][q=ln16]
    float m_i = -1e30f, l_i = 0.f;   // per-lane: q = ln16 (replicated across quads)

    const int kv_lo = ch * CHUNK;
    const int kv_hi = min(kv_lo + CHUNK, qt * 64 + 64);
    for (int kv0 = kv_lo; kv0 < kv_hi; kv0 += 64) {
        float p[4][4];
        float mx = -1e30f;
        #pragma unroll
        for (int g = 0; g < 4; g++) {
            // S^T = K Q^T: A = K rows (A[m=kv_local=ln16][k=d=quad*8+j])
            const u16* krp = kbb + (size_t)(kv0 + g * 16 + ln16) * HEAD + quad * 8;
            f32x4 s = {};
            s = mfma16(ld8(krp), qf0, s);
            s = mfma16(ld8(krp + 32), qf1, s);
            #pragma unroll
            for (int r = 0; r < 4; r++) {   // S^T[kv=g*16+quad*4+r][q=ln16]
                int kv = kv0 + g * 16 + quad * 4 + r;
                float v = s[r] * 0.125f;
                v = (kv <= qrow) ? v : -1e30f;
                p[g][r] = v;
                mx = fmaxf(mx, v);
            }
        }
        mx = fmaxf(mx, __shfl_xor(mx, 16));   // reduce across quads only
        mx = fmaxf(mx, __shfl_xor(mx, 32));
        float m_new = fmaxf(m_i, mx);
        float alpha = __expf(m_i - m_new);
        float ps = 0.f;
        #pragma unroll
        for (int g = 0; g < 4; g++)
            #pragma unroll
            for (int r = 0; r < 4; r++) {
                p[g][r] = __expf(p[g][r] - m_new);
                ps += p[g][r];
            }
        ps += __shfl_xor(ps, 16);
        ps += __shfl_xor(ps, 32);
        l_i = l_i * alpha + ps;
        m_i = m_new;
        #pragma unroll
        for (int hg = 0; hg < 4; hg++) {
            o[hg][0] *= alpha; o[hg][1] *= alpha; o[hg][2] *= alpha; o[hg][3] *= alpha;
        }
        // P^T -> LDS as P[q=ln16][kv], 8B packed stores (r consecutive in kv)
        #pragma unroll
        for (int g = 0; g < 4; g++) {
            uint32_t lo = (uint32_t)f2bf(p[g][0]) | ((uint32_t)f2bf(p[g][1]) << 16);
            uint32_t hi = (uint32_t)f2bf(p[g][2]) | ((uint32_t)f2bf(p[g][3]) << 16);
            uint32_t* dst = (uint32_t*)&P[ln16][g * 16 + quad * 4];
            dst[0] = lo; dst[1] = hi;
        }
        // same-wave LDS write->read is ordered; no barrier needed
        bf16x8 pf0 = ld8(&P[ln16][quad * 8]);        // B[k=kv=quad*8+j][n=q=ln16]
        bf16x8 pf1 = ld8(&P[ln16][32 + quad * 8]);
        #pragma unroll
        for (int hg = 0; hg < 4; hg++) {             // O^T = V^T P^T: A = vT rows
            const u16* vrp = vbb + (size_t)(hg * 16 + ln16) * L_SEQ + kv0 + quad * 8;
            o[hg] = mfma16(ld8(vrp), pf0, o[hg]);
            o[hg] = mfma16(ld8(vrp + 32), pf1, o[hg]);
        }
    }
    // partials: Opart[b][qt][ch][q_local][h] fp32, float4 stores
    size_t base = (size_t)((b * 64 + qt) * MAXCH + ch) * 4096;
    #pragma unroll
    for (int hg = 0; hg < 4; hg++)
        *(f32x4*)&Opart[base + (size_t)ln16 * 64 + (size_t)(wv) * 0 + hg * 16 + quad * 4 + (size_t)q_local * 64 - (size_t)ln16 * 64] = o[hg];
    if (quad == 0) {
        size_t mb = (size_t)((b * 64 + qt) * MAXCH + ch) * 128 + q_local * 2;
        ml[mb] = m_i; ml[mb + 1] = l_i;
    }
}

// --- Kernel 3: merge split-KV partials
__global__ __launch_bounds__(256) void merge_chunks(
    const float* __restrict__ Opart, const float* __restrict__ ml, float* __restrict__ out)
{
    const int qt = blockIdx.x, b = blockIdx.y;
    const int nch = qt / 8 + 1;
    const int t = threadIdx.x;
    const int h = t & 63, rg = t >> 6;
    const size_t obase = (size_t)((b * 64 + qt) * MAXCH) * 4096;
    const size_t mbase = (size_t)((b * 64 + qt) * MAXCH) * 128;
    for (int p = 0; p < 16; p++) {
        int q = p * 4 + rg;
        float M = -1e30f;
        for (int c = 0; c < nch; c++)
            M = fmaxf(M, ml[mbase + c * 128 + q * 2]);
        float L = 0.f, acc = 0.f;
        for (int c = 0; c < nch; c++) {
            float m = ml[mbase + c * 128 + q * 2];
            float l = ml[mbase + c * 128 + q * 2 + 1];
            float w = __expf(m - M);
            L += w * l;
            acc += w * Opart[obase + (size_t)c * 4096 + q * 64 + h];
        }
        out[((size_t)(b * L_SEQ + qt * 64 + q)) * HEAD + h] = acc / L;
    }
}

extern "C" void kernel_launch(void* const* d_in, const int* in_sizes, int n_in,
                              void* d_out, int out_size, void* d_ws, size_t ws_size,
                              hipStream_t stream) {
    const float* x  = (const float*)d_in[0];
    const float* Wq = (const float*)d_in[1];
    const float* Wk = (const float*)d_in[2];
    const float* Wv = (const float*)d_in[3];
    float* out = (float*)d_out;

    u16* ws16 = (u16*)d_ws;
    u16* Wt  = ws16;                          // 3*64*1024
    u16* qb  = Wt + 3 * HEAD * D_MODEL;       // [4,4096,64]
    u16* kb  = qb + 16384 * HEAD;
    u16* vTb = kb + 16384 * HEAD;             // [4,64,4096]
    float* Opart = (float*)(vTb + 16384 * HEAD);   // [4*64*8][4096] = 32 MB
    float* ml    = Opart + (size_t)2048 * 4096;    // [4*64*8][128]  = 1 MB

    conv_w      <<<dim3(16, 3), 256, 0, stream>>>(Wq, Wk, Wv, Wt);
    qkv_proj    <<<dim3(512), 256, 0, stream>>>(x, Wt, qb, kb, vTb);
    attn_chunk  <<<dim3(8, 64, 4), 256, 0, stream>>>(qb, kb, vTb, Opart, ml);
    merge_chunks<<<dim3(64, 4), 256, 0, stream>>>(Opart, ml, out);
}

// Round 4
// 281.073 us; speedup vs baseline: 1.4180x; 1.1359x over previous
//
#include <hip/hip_runtime.h>
#include <stdint.h>

#define L_SEQ 4096
#define D_MODEL 1024
#define HEAD 64
#define CHUNK 512
#define MAXCH 8

typedef unsigned short u16;
typedef __attribute__((ext_vector_type(8))) short bf16x8;
typedef __attribute__((ext_vector_type(4))) float f32x4;

static __device__ __forceinline__ u16 f2bf(float f) {
    union { float f; uint32_t u; } c; c.f = f;
    uint32_t u = c.u;
    return (u16)((u + 0x7FFFu + ((u >> 16) & 1u)) >> 16);
}
static __device__ __forceinline__ bf16x8 ld8(const u16* p) { return *(const bf16x8*)p; }

static __device__ __forceinline__ bf16x8 cvt8(const float* p) {
    const float4* q = (const float4*)p;
    float4 a = q[0], b = q[1];
    bf16x8 r;
    r[0] = (short)f2bf(a.x); r[1] = (short)f2bf(a.y);
    r[2] = (short)f2bf(a.z); r[3] = (short)f2bf(a.w);
    r[4] = (short)f2bf(b.x); r[5] = (short)f2bf(b.y);
    r[6] = (short)f2bf(b.z); r[7] = (short)f2bf(b.w);
    return r;
}
static __device__ __forceinline__ f32x4 mfma16(bf16x8 a, bf16x8 b, f32x4 c) {
    return __builtin_amdgcn_mfma_f32_16x16x32_bf16(a, b, c, 0, 0, 0);
}

// --- Kernel 0: W fp32 [1024,64] -> bf16 Wt [64,1024] x3, LDS transpose
__global__ __launch_bounds__(256) void conv_w(
    const float* __restrict__ Wq, const float* __restrict__ Wk,
    const float* __restrict__ Wv, u16* __restrict__ Wt)
{
    __shared__ u16 tile[64][72];
    const float* W = (blockIdx.y == 0) ? Wq : (blockIdx.y == 1) ? Wk : Wv;
    u16* dst = Wt + blockIdx.y * (HEAD * D_MODEL);
    const int k0 = blockIdx.x * 64, t = threadIdx.x;
    #pragma unroll
    for (int i = 0; i < 16; i++) {
        int idx = i * 256 + t;
        int kk = idx >> 6, h = idx & 63;
        tile[h][kk] = f2bf(W[(size_t)(k0 + kk) * HEAD + h]);
    }
    __syncthreads();
    #pragma unroll
    for (int i = 0; i < 16; i++) {
        int idx = i * 256 + t;
        int h = idx >> 6, kk = idx & 63;
        dst[(size_t)h * D_MODEL + k0 + kk] = tile[h][kk];
    }
}

// --- Kernel 1: fused QKV projection, 512 blocks = 2 m-tiles x 2 K-halves.
// q is pre-scaled by 1/8 (softmax scale). All outputs staged via LDS for
// coalesced 16B stores.
__global__ __launch_bounds__(256) void qkv_proj(
    const float* __restrict__ x, const u16* __restrict__ Wt,
    u16* __restrict__ qb, u16* __restrict__ kb, u16* __restrict__ vTb)
{
    __shared__ __align__(16) float accbuf[2][12][64][4];   // 24 KB
    __shared__ __align__(16) u16 qtile[32][72];            // 4.5 KB
    __shared__ __align__(16) u16 ktile[32][72];            // 4.5 KB
    __shared__ __align__(16) u16 vtile[64][40];            // 5 KB
    const int t = threadIdx.x;
    const int wv = t >> 6, lane = t & 63;
    const int ln16 = lane & 15, quad = lane >> 4;
    const int mt = wv & 1, kh = wv >> 1;
    const int mbase = blockIdx.x * 32 + mt * 16;

    f32x4 acc[12] = {};
    const float* arow = x + (size_t)(mbase + ln16) * D_MODEL + kh * 512 + quad * 8;
    const u16* brow = Wt + (size_t)ln16 * D_MODEL + kh * 512 + quad * 8;
    for (int k0 = 0; k0 < 512; k0 += 32) {
        bf16x8 a = cvt8(arow + k0);
        #pragma unroll
        for (int i = 0; i < 12; i++) {
            bf16x8 b = ld8(brow + (size_t)(i * 16) * D_MODEL + k0);
            acc[i] = mfma16(a, b, acc[i]);
        }
    }
    if (kh == 1) {
        #pragma unroll
        for (int i = 0; i < 12; i++)
            *(f32x4*)&accbuf[mt][i][lane][0] = acc[i];
    }
    __syncthreads();
    if (kh == 0) {
        #pragma unroll
        for (int i = 0; i < 12; i++) {
            f32x4 o = *(f32x4*)&accbuf[mt][i][lane][0];
            acc[i][0] += o[0]; acc[i][1] += o[1]; acc[i][2] += o[2]; acc[i][3] += o[3];
        }
        #pragma unroll
        for (int i = 0; i < 12; i++) {
            int w = i >> 2, nt = i & 3;
            #pragma unroll
            for (int r = 0; r < 4; r++) {
                int mrow = mt * 16 + quad * 4 + r;     // C/D: col=ln16, row=quad*4+r
                int h = nt * 16 + ln16;
                if (w == 0)      qtile[mrow][h] = f2bf(acc[i][r] * 0.125f);
                else if (w == 1) ktile[mrow][h] = f2bf(acc[i][r]);
                else             vtile[h][mrow] = f2bf(acc[i][r]);
            }
        }
    }
    __syncthreads();
    {   // coalesced stores
        int mrow = t >> 3, hseg = (t & 7) * 8;
        size_t m = blockIdx.x * 32 + mrow;
        *(bf16x8*)&qb[m * HEAD + hseg] = *(bf16x8*)&qtile[mrow][hseg];
        *(bf16x8*)&kb[m * HEAD + hseg] = *(bf16x8*)&ktile[mrow][hseg];
        int h = t >> 2, mloc = (t & 3) * 8;
        int mg = blockIdx.x * 32 + mloc;
        int bb = mg >> 12, l = mg & 4095;
        *(bf16x8*)&vTb[(size_t)(bb * HEAD + h) * L_SEQ + l] = *(bf16x8*)&vtile[h][mloc];
    }
}

// --- Kernel 2: split-KV causal attention, transposed-S, max-free softmax.
// grid (qt=64, ch=8, b=4): id%8 = qt%8 -> XCD-balanced. No in-loop shuffles.
__global__ __launch_bounds__(256) void attn_chunk(
    const u16* __restrict__ qb, const u16* __restrict__ kb,
    const u16* __restrict__ vT, float* __restrict__ Opart, float* __restrict__ lpart)
{
    const int qt = blockIdx.x, ch = blockIdx.y, b = blockIdx.z;
    if (ch * CHUNK > qt * 64 + 63) return;
    const int t = threadIdx.x, wv = t >> 6, lane = t & 63;
    const int ln16 = lane & 15, quad = lane >> 4;
    const int q_local = wv * 16 + ln16;
    const int qrow = qt * 64 + q_local;

    __shared__ __align__(16) u16 Pb[4][16][72];   // per-wave P tile
    u16 (*P)[72] = Pb[wv];

    // Q enters as B-operand: B[k=d=quad*8+j][n=q=ln16]; q pre-scaled by 1/8
    const u16* qrp = qb + (size_t)(b * L_SEQ + qrow) * HEAD + quad * 8;
    bf16x8 qf0 = ld8(qrp), qf1 = ld8(qrp + 32);

    const u16* kbb = kb + (size_t)b * L_SEQ * HEAD;
    const u16* vbb = vT + (size_t)b * HEAD * L_SEQ;

    f32x4 o[4] = {};          // O^T[h=hg*16+quad*4+r][q=ln16]
    float lsum = 0.f;         // per-lane partial of l (q=ln16, split across quads)

    const int kv_lo = ch * CHUNK;
    const int kv_hi = min(kv_lo + CHUNK, qt * 64 + 64);
    const int wave_qmin = qt * 64 + wv * 16;

    for (int kv0 = kv_lo; kv0 < kv_hi; kv0 += 64) {
        f32x4 s[4];
        #pragma unroll
        for (int g = 0; g < 4; g++) {
            // S^T = K Q^T: A = K rows A[m=kv=ln16][k=d=quad*8+j]
            const u16* krp = kbb + (size_t)(kv0 + g * 16 + ln16) * HEAD + quad * 8;
            f32x4 acc = {};
            acc = mfma16(ld8(krp), qf0, acc);
            acc = mfma16(ld8(krp + 32), qf1, acc);
            s[g] = acc;   // S^T[kv=kv0+g*16+quad*4+r][q=ln16]
        }
        float p[4][4];
        if (kv0 + 63 <= wave_qmin) {          // wave-uniform: fully unmasked
            #pragma unroll
            for (int g = 0; g < 4; g++)
                #pragma unroll
                for (int r = 0; r < 4; r++) {
                    p[g][r] = __expf(s[g][r]);
                    lsum += p[g][r];
                }
        } else {
            #pragma unroll
            for (int g = 0; g < 4; g++)
                #pragma unroll
                for (int r = 0; r < 4; r++) {
                    int kv = kv0 + g * 16 + quad * 4 + r;
                    float e = __expf(s[g][r]);
                    e = (kv <= qrow) ? e : 0.f;
                    p[g][r] = e;
                    lsum += e;
                }
        }
        // P^T -> LDS as P[q=ln16][kv] (8B packed, 2-way bank alias = free)
        #pragma unroll
        for (int g = 0; g < 4; g++) {
            uint32_t lo = (uint32_t)f2bf(p[g][0]) | ((uint32_t)f2bf(p[g][1]) << 16);
            uint32_t hi = (uint32_t)f2bf(p[g][2]) | ((uint32_t)f2bf(p[g][3]) << 16);
            uint32_t* dst = (uint32_t*)&P[ln16][g * 16 + quad * 4];
            dst[0] = lo; dst[1] = hi;
        }
        // same-wave LDS write->read: ordered, no barrier
        bf16x8 pf0 = ld8(&P[ln16][quad * 8]);
        bf16x8 pf1 = ld8(&P[ln16][32 + quad * 8]);
        #pragma unroll
        for (int hg = 0; hg < 4; hg++) {      // O^T = V^T P^T: A = vT rows
            const u16* vrp = vbb + (size_t)(hg * 16 + ln16) * L_SEQ + kv0 + quad * 8;
            o[hg] = mfma16(ld8(vrp), pf0, o[hg]);
            o[hg] = mfma16(ld8(vrp + 32), pf1, o[hg]);
        }
    }

    lsum += __shfl_xor(lsum, 16);   // combine quad partials (once per kernel)
    lsum += __shfl_xor(lsum, 32);

    const size_t base = (size_t)((b * 64 + qt) * MAXCH + ch);
    #pragma unroll
    for (int hg = 0; hg < 4; hg++)
        *(f32x4*)&Opart[base * 4096 + (size_t)q_local * 64 + hg * 16 + quad * 4] = o[hg];
    if (quad == 0)
        lpart[base * 64 + q_local] = lsum;
}

// --- Kernel 3: merge partials (no exp needed: m == 0 everywhere)
__global__ __launch_bounds__(256) void merge_chunks(
    const float* __restrict__ Opart, const float* __restrict__ lpart,
    float* __restrict__ out)
{
    const int qt = blockIdx.x, b = blockIdx.y;
    const int nch = qt / 8 + 1;
    const int t = threadIdx.x;
    const int h = t & 63, rg = t >> 6;
    const size_t obase = (size_t)((b * 64 + qt) * MAXCH) * 4096;
    const size_t lbase = (size_t)((b * 64 + qt) * MAXCH) * 64;
    for (int pp = 0; pp < 16; pp++) {
        int q = pp * 4 + rg;
        float L = 0.f, acc = 0.f;
        for (int c = 0; c < nch; c++) {
            L += lpart[lbase + c * 64 + q];
            acc += Opart[obase + (size_t)c * 4096 + q * 64 + h];
        }
        out[((size_t)(b * L_SEQ + qt * 64 + q)) * HEAD + h] = acc / L;
    }
}

extern "C" void kernel_launch(void* const* d_in, const int* in_sizes, int n_in,
                              void* d_out, int out_size, void* d_ws, size_t ws_size,
                              hipStream_t stream) {
    const float* x  = (const float*)d_in[0];
    const float* Wq = (const float*)d_in[1];
    const float* Wk = (const float*)d_in[2];
    const float* Wv = (const float*)d_in[3];
    float* out = (float*)d_out;

    u16* ws16 = (u16*)d_ws;
    u16* Wt  = ws16;                          // 3*64*1024
    u16* qb  = Wt + 3 * HEAD * D_MODEL;       // [4,4096,64]
    u16* kb  = qb + 16384 * HEAD;
    u16* vTb = kb + 16384 * HEAD;             // [4,64,4096]
    float* Opart = (float*)(vTb + 16384 * HEAD);   // [2048][4096] fp32 = 32 MB
    float* lpart = Opart + (size_t)2048 * 4096;    // [2048][64] fp32

    conv_w      <<<dim3(16, 3), 256, 0, stream>>>(Wq, Wk, Wv, Wt);
    qkv_proj    <<<dim3(512), 256, 0, stream>>>(x, Wt, qb, kb, vTb);
    attn_chunk  <<<dim3(64, 8, 4), 256, 0, stream>>>(qb, kb, vTb, Opart, lpart);
    merge_chunks<<<dim3(64, 4), 256, 0, stream>>>(Opart, lpart, out);
}

// Round 5
// 232.200 us; speedup vs baseline: 1.7165x; 1.2105x over previous
//
#include <hip/hip_runtime.h>
#include <stdint.h>

#define L_SEQ 4096
#define D_MODEL 1024
#define HEAD 64
#define CHUNK 512
#define MAXCH 8

typedef unsigned short u16;
typedef __attribute__((ext_vector_type(8))) short bf16x8;
typedef __attribute__((ext_vector_type(4))) float f32x4;

static __device__ __forceinline__ u16 f2bf(float f) {
    union { float f; uint32_t u; } c; c.f = f;
    uint32_t u = c.u;
    return (u16)((u + 0x7FFFu + ((u >> 16) & 1u)) >> 16);
}
static __device__ __forceinline__ bf16x8 ld8(const u16* p) { return *(const bf16x8*)p; }

static __device__ __forceinline__ bf16x8 pack8(float4 a, float4 b) {
    bf16x8 r;
    r[0] = (short)f2bf(a.x); r[1] = (short)f2bf(a.y);
    r[2] = (short)f2bf(a.z); r[3] = (short)f2bf(a.w);
    r[4] = (short)f2bf(b.x); r[5] = (short)f2bf(b.y);
    r[6] = (short)f2bf(b.z); r[7] = (short)f2bf(b.w);
    return r;
}
static __device__ __forceinline__ f32x4 mfma16(bf16x8 a, bf16x8 b, f32x4 c) {
    return __builtin_amdgcn_mfma_f32_16x16x32_bf16(a, b, c, 0, 0, 0);
}

// --- Kernel 0: W fp32 [1024,64] -> bf16 Wt [64,1024] x3, LDS transpose
__global__ __launch_bounds__(256) void conv_w(
    const float* __restrict__ Wq, const float* __restrict__ Wk,
    const float* __restrict__ Wv, u16* __restrict__ Wt)
{
    __shared__ u16 tile[64][72];
    const float* W = (blockIdx.y == 0) ? Wq : (blockIdx.y == 1) ? Wk : Wv;
    u16* dst = Wt + blockIdx.y * (HEAD * D_MODEL);
    const int k0 = blockIdx.x * 64, t = threadIdx.x;
    #pragma unroll
    for (int i = 0; i < 16; i++) {
        int idx = i * 256 + t;
        int kk = idx >> 6, h = idx & 63;
        tile[h][kk] = f2bf(W[(size_t)(k0 + kk) * HEAD + h]);
    }
    __syncthreads();
    #pragma unroll
    for (int i = 0; i < 16; i++) {
        int idx = i * 256 + t;
        int h = idx >> 6, kk = idx & 63;
        dst[(size_t)h * D_MODEL + k0 + kk] = tile[h][kk];
    }
}

// --- Kernel 1: fused QKV projection. 1024 blocks = 16 rows, 4 waves = 4-way
// K-split (256 K each), explicit x prefetch, LDS fp32 combine. q pre-scaled 1/8.
__global__ __launch_bounds__(256) void qkv_proj(
    const float* __restrict__ x, const u16* __restrict__ Wt,
    u16* __restrict__ qb, u16* __restrict__ kb, u16* __restrict__ vTb)
{
    __shared__ __align__(16) float bufs[3][12][64][4];     // 36 KB
    __shared__ __align__(16) u16 qtile[16][72];
    __shared__ __align__(16) u16 ktile[16][72];
    __shared__ __align__(16) u16 vtile[64][24];
    const int t = threadIdx.x;
    const int wv = t >> 6, lane = t & 63;
    const int ln16 = lane & 15, quad = lane >> 4;
    const int mbase = blockIdx.x * 16;

    f32x4 acc[12] = {};
    const float* arow = x + (size_t)(mbase + ln16) * D_MODEL + wv * 256 + quad * 8;
    const u16* brow = Wt + (size_t)ln16 * D_MODEL + wv * 256 + quad * 8;

    const float4* ap = (const float4*)arow;
    float4 xa = ap[0], xb = ap[1];
    for (int k0 = 0; k0 < 256; k0 += 32) {
        int k0n = (k0 + 32 < 256) ? k0 + 32 : 0;
        const float4* np = (const float4*)(arow + k0n);
        float4 na = np[0], nb = np[1];               // prefetch next x slice
        bf16x8 a = pack8(xa, xb);
        #pragma unroll
        for (int i = 0; i < 12; i++) {
            bf16x8 b = ld8(brow + (size_t)(i * 16) * D_MODEL + k0);
            acc[i] = mfma16(a, b, acc[i]);
        }
        xa = na; xb = nb;
    }
    if (wv != 0) {
        #pragma unroll
        for (int i = 0; i < 12; i++)
            *(f32x4*)&bufs[wv - 1][i][lane][0] = acc[i];
    }
    __syncthreads();
    if (wv == 0) {
        #pragma unroll
        for (int i = 0; i < 12; i++) {
            #pragma unroll
            for (int w = 0; w < 3; w++) {
                f32x4 o = *(f32x4*)&bufs[w][i][lane][0];
                acc[i][0] += o[0]; acc[i][1] += o[1];
                acc[i][2] += o[2]; acc[i][3] += o[3];
            }
        }
        #pragma unroll
        for (int i = 0; i < 12; i++) {
            int w = i >> 2, nt = i & 3;
            #pragma unroll
            for (int r = 0; r < 4; r++) {
                int mrow = quad * 4 + r;          // C/D: col=ln16, row=quad*4+r
                int h = nt * 16 + ln16;
                if (w == 0)      qtile[mrow][h] = f2bf(acc[i][r] * 0.125f);
                else if (w == 1) ktile[mrow][h] = f2bf(acc[i][r]);
                else             vtile[h][mrow] = f2bf(acc[i][r]);
            }
        }
    }
    __syncthreads();
    {   // cooperative coalesced stores
        int tt = t & 127;
        int mrow = tt >> 3, hseg = (tt & 7) * 8;
        size_t m = (size_t)blockIdx.x * 16 + mrow;
        if (t < 128)
            *(bf16x8*)&qb[m * HEAD + hseg] = *(bf16x8*)&qtile[mrow][hseg];
        else
            *(bf16x8*)&kb[m * HEAD + hseg] = *(bf16x8*)&ktile[mrow][hseg];
        if (t < 128) {
            int h = t >> 1, mloc = (t & 1) * 8;
            int mg = blockIdx.x * 16 + mloc;
            int bb = mg >> 12, l = mg & 4095;
            *(bf16x8*)&vTb[(size_t)(bb * HEAD + h) * L_SEQ + l] = *(bf16x8*)&vtile[h][mloc];
        }
    }
}

// --- Kernel 2: split-KV causal attention, 2x2 wave split.
// grid (qt=64, ch=8, b=4). Block = 4 waves: (q-half 32 rows) x (kv-half 256).
// Serial chain per wave: <=4 kv-tiles of 64. P round-trip same-wave (no barrier
// in loop); kv-halves combined in LDS after the loop.
__global__ __launch_bounds__(256) void attn_chunk(
    const u16* __restrict__ qb, const u16* __restrict__ kb,
    const u16* __restrict__ vT, float* __restrict__ Opart, float* __restrict__ lpart)
{
    const int qt = blockIdx.x, ch = blockIdx.y, b = blockIdx.z;
    if (ch * CHUNK > qt * 64 + 63) return;

    __shared__ __align__(16) char smem[18432];   // loop: P[4][32][72] u16; after: Cb[64][68]+Lb[64] f32

    const int t = threadIdx.x, wv = t >> 6, lane = t & 63;
    const int ln16 = lane & 15, quad = lane >> 4;
    const int qh = wv & 1, kvh = wv >> 1;
    const int qmin0 = qt * 64 + qh * 32;         // wave's lowest q row

    u16 (*P)[72] = (u16(*)[72])smem + wv * 32;   // wave-private 32x72
    float (*Cb)[68] = (float(*)[68])smem;        // combine: [qh*32+q][h]
    float* Lb = (float*)(smem + 17408);          // combine: [qh*32+q]

    // Q as B-operand: B[k=d=quad*8+j][n=q=ln16]; q pre-scaled 1/8
    bf16x8 qf[2][2];
    #pragma unroll
    for (int qn = 0; qn < 2; qn++) {
        const u16* qrp = qb + (size_t)(b * L_SEQ + qmin0 + qn * 16 + ln16) * HEAD + quad * 8;
        qf[qn][0] = ld8(qrp); qf[qn][1] = ld8(qrp + 32);
    }

    const u16* kbb = kb + (size_t)b * L_SEQ * HEAD;
    const u16* vbb = vT + (size_t)b * HEAD * L_SEQ;

    f32x4 o[2][4] = {};          // O^T[h=hg*16+quad*4+r][q=qn*16+ln16]
    float lsum[2] = {0.f, 0.f};

    const int kv_lo = ch * CHUNK + kvh * (CHUNK / 2);
    const int kv_hi = min(kv_lo + CHUNK / 2, qt * 64 + 64);

    bf16x8 kf0a, kf0b, kf1a, kf1b;               // g=0,1 K frags (prefetched)
    if (kv_lo < kv_hi) {
        const u16* kr0 = kbb + (size_t)(kv_lo + ln16) * HEAD + quad * 8;
        kf0a = ld8(kr0); kf0b = ld8(kr0 + 32);
        const u16* kr1 = kbb + (size_t)(kv_lo + 16 + ln16) * HEAD + quad * 8;
        kf1a = ld8(kr1); kf1b = ld8(kr1 + 32);
    }

    for (int kv0 = kv_lo; kv0 < kv_hi; kv0 += 64) {
        // --- issue all independent loads first ---
        const u16* kr2 = kbb + (size_t)(kv0 + 32 + ln16) * HEAD + quad * 8;
        bf16x8 kf2a = ld8(kr2), kf2b = ld8(kr2 + 32);
        const u16* kr3 = kbb + (size_t)(kv0 + 48 + ln16) * HEAD + quad * 8;
        bf16x8 kf3a = ld8(kr3), kf3b = ld8(kr3 + 32);
        int kv0n = (kv0 + 64 < kv_hi) ? kv0 + 64 : kv_lo;   // next-tile K (g=0,1)
        const u16* nr0 = kbb + (size_t)(kv0n + ln16) * HEAD + quad * 8;
        bf16x8 nk0a = ld8(nr0), nk0b = ld8(nr0 + 32);
        const u16* nr1 = kbb + (size_t)(kv0n + 16 + ln16) * HEAD + quad * 8;
        bf16x8 nk1a = ld8(nr1), nk1b = ld8(nr1 + 32);
        const u16* vr0 = vbb + (size_t)ln16 * L_SEQ + kv0 + quad * 8;
        bf16x8 vf0a = ld8(vr0), vf0b = ld8(vr0 + 32);       // hg=0 V early
        const u16* vr1 = vbb + (size_t)(16 + ln16) * L_SEQ + kv0 + quad * 8;
        bf16x8 vf1a = ld8(vr1), vf1b = ld8(vr1 + 32);       // hg=1 V early

        // --- S^T = K Q^T per g-group; exp; P store (same-wave LDS) ---
        #pragma unroll
        for (int g = 0; g < 4; g++) {
            bf16x8 ka = (g == 0) ? kf0a : (g == 1) ? kf1a : (g == 2) ? kf2a : kf3a;
            bf16x8 kb8 = (g == 0) ? kf0b : (g == 1) ? kf1b : (g == 2) ? kf2b : kf3b;
            #pragma unroll
            for (int qn = 0; qn < 2; qn++) {
                f32x4 s = {};
                s = mfma16(ka, qf[qn][0], s);
                s = mfma16(kb8, qf[qn][1], s);
                // S^T[kv=kv0+g*16+quad*4+r][q=qmin0+qn*16+ln16]
                float p0, p1, p2, p3;
                if (kv0 + g * 16 + 15 <= qmin0 + qn * 16) {  // fully unmasked
                    p0 = __expf(s[0]); p1 = __expf(s[1]);
                    p2 = __expf(s[2]); p3 = __expf(s[3]);
                } else {
                    int q = qmin0 + qn * 16 + ln16;
                    int kv = kv0 + g * 16 + quad * 4;
                    p0 = (kv     <= q) ? __expf(s[0]) : 0.f;
                    p1 = (kv + 1 <= q) ? __expf(s[1]) : 0.f;
                    p2 = (kv + 2 <= q) ? __expf(s[2]) : 0.f;
                    p3 = (kv + 3 <= q) ? __expf(s[3]) : 0.f;
                }
                lsum[qn] += p0 + p1 + p2 + p3;
                uint32_t lo = (uint32_t)f2bf(p0) | ((uint32_t)f2bf(p1) << 16);
                uint32_t hi = (uint32_t)f2bf(p2) | ((uint32_t)f2bf(p3) << 16);
                uint32_t* dst = (uint32_t*)&P[qn * 16 + ln16][g * 16 + quad * 4];
                dst[0] = lo; dst[1] = hi;
            }
        }
        // --- P back as B-operand (same-wave, ordered) ---
        bf16x8 pf0[2], pf1[2];
        #pragma unroll
        for (int qn = 0; qn < 2; qn++) {
            pf0[qn] = ld8(&P[qn * 16 + ln16][quad * 8]);
            pf1[qn] = ld8(&P[qn * 16 + ln16][32 + quad * 8]);
        }
        // --- O^T += V^T P^T ---
        #pragma unroll
        for (int hg = 0; hg < 4; hg++) {
            bf16x8 va, vb2;
            if (hg == 0) { va = vf0a; vb2 = vf0b; }
            else if (hg == 1) { va = vf1a; vb2 = vf1b; }
            else {
                const u16* vr = vbb + (size_t)(hg * 16 + ln16) * L_SEQ + kv0 + quad * 8;
                va = ld8(vr); vb2 = ld8(vr + 32);
            }
            #pragma unroll
            for (int qn = 0; qn < 2; qn++) {
                o[qn][hg] = mfma16(va, pf0[qn], o[qn][hg]);
                o[qn][hg] = mfma16(vb2, pf1[qn], o[qn][hg]);
            }
        }
        kf0a = nk0a; kf0b = nk0b; kf1a = nk1a; kf1b = nk1b;
    }

    #pragma unroll
    for (int qn = 0; qn < 2; qn++) {             // full l over this wave's kv half
        lsum[qn] += __shfl_xor(lsum[qn], 16);
        lsum[qn] += __shfl_xor(lsum[qn], 32);
    }

    __syncthreads();                             // P dead; smem becomes Cb/Lb
    if (kvh == 1) {
        #pragma unroll
        for (int qn = 0; qn < 2; qn++) {
            #pragma unroll
            for (int hg = 0; hg < 4; hg++)
                *(f32x4*)&Cb[qh * 32 + qn * 16 + ln16][hg * 16 + quad * 4] = o[qn][hg];
            if (quad == 0) Lb[qh * 32 + qn * 16 + ln16] = lsum[qn];
        }
    }
    __syncthreads();
    if (kvh == 0) {
        const size_t base = (size_t)((b * 64 + qt) * MAXCH + ch);
        #pragma unroll
        for (int qn = 0; qn < 2; qn++) {
            int qrow = qh * 32 + qn * 16 + ln16;
            #pragma unroll
            for (int hg = 0; hg < 4; hg++) {
                f32x4 other = *(f32x4*)&Cb[qrow][hg * 16 + quad * 4];
                f32x4 r = o[qn][hg];
                r[0] += other[0]; r[1] += other[1]; r[2] += other[2]; r[3] += other[3];
                *(f32x4*)&Opart[base * 4096 + (size_t)qrow * 64 + hg * 16 + quad * 4] = r;
            }
            if (quad == 0)
                lpart[base * 64 + qrow] = lsum[qn] + Lb[qrow];
        }
    }
}

// --- Kernel 3: merge partials (max-free: m == 0 everywhere)
__global__ __launch_bounds__(256) void merge_chunks(
    const float* __restrict__ Opart, const float* __restrict__ lpart,
    float* __restrict__ out)
{
    const int qt = blockIdx.x, b = blockIdx.y;
    const int nch = qt / 8 + 1;
    const int t = threadIdx.x;
    const int h = t & 63, rg = t >> 6;
    const size_t obase = (size_t)((b * 64 + qt) * MAXCH) * 4096;
    const size_t lbase = (size_t)((b * 64 + qt) * MAXCH) * 64;
    for (int pp = 0; pp < 16; pp++) {
        int q = pp * 4 + rg;
        float L = 0.f, acc = 0.f;
        for (int c = 0; c < nch; c++) {
            L += lpart[lbase + c * 64 + q];
            acc += Opart[obase + (size_t)c * 4096 + q * 64 + h];
        }
        out[((size_t)(b * L_SEQ + qt * 64 + q)) * HEAD + h] = acc / L;
    }
}

extern "C" void kernel_launch(void* const* d_in, const int* in_sizes, int n_in,
                              void* d_out, int out_size, void* d_ws, size_t ws_size,
                              hipStream_t stream) {
    const float* x  = (const float*)d_in[0];
    const float* Wq = (const float*)d_in[1];
    const float* Wk = (const float*)d_in[2];
    const float* Wv = (const float*)d_in[3];
    float* out = (float*)d_out;

    u16* ws16 = (u16*)d_ws;
    u16* Wt  = ws16;                          // 3*64*1024
    u16* qb  = Wt + 3 * HEAD * D_MODEL;       // [4,4096,64]
    u16* kb  = qb + 16384 * HEAD;
    u16* vTb = kb + 16384 * HEAD;             // [4,64,4096]
    float* Opart = (float*)(vTb + 16384 * HEAD);   // [2048][4096] fp32 = 32 MB
    float* lpart = Opart + (size_t)2048 * 4096;    // [2048][64] fp32

    conv_w      <<<dim3(16, 3), 256, 0, stream>>>(Wq, Wk, Wv, Wt);
    qkv_proj    <<<dim3(1024), 256, 0, stream>>>(x, Wt, qb, kb, vTb);
    attn_chunk  <<<dim3(64, 8, 4), 256, 0, stream>>>(qb, kb, vTb, Opart, lpart);
    merge_chunks<<<dim3(64, 4), 256, 0, stream>>>(Opart, lpart, out);
}

// Round 6
// 175.514 us; speedup vs baseline: 2.2709x; 1.3230x over previous
//
#include <hip/hip_runtime.h>
#include <stdint.h>

#define L_SEQ 4096
#define D_MODEL 1024
#define HEAD 64
#define CHUNK 512
#define MAXCH 8

typedef unsigned short u16;
typedef __attribute__((ext_vector_type(8))) short bf16x8;
typedef __attribute__((ext_vector_type(4))) float f32x4;

static __device__ __forceinline__ u16 f2bf(float f) {
    union { float f; uint32_t u; } c; c.f = f;
    uint32_t u = c.u;
    return (u16)((u + 0x7FFFu + ((u >> 16) & 1u)) >> 16);
}
static __device__ __forceinline__ bf16x8 ld8(const u16* p) { return *(const bf16x8*)p; }

static __device__ __forceinline__ f32x4 mfma16(bf16x8 a, bf16x8 b, f32x4 c) {
    return __builtin_amdgcn_mfma_f32_16x16x32_bf16(a, b, c, 0, 0, 0);
}

// --- Kernel 0: W fp32 [1024,64] -> bf16 Wt [64,1024] x3, LDS transpose
__global__ __launch_bounds__(256) void conv_w(
    const float* __restrict__ Wq, const float* __restrict__ Wk,
    const float* __restrict__ Wv, u16* __restrict__ Wt)
{
    __shared__ u16 tile[64][72];
    const float* W = (blockIdx.y == 0) ? Wq : (blockIdx.y == 1) ? Wk : Wv;
    u16* dst = Wt + blockIdx.y * (HEAD * D_MODEL);
    const int k0 = blockIdx.x * 64, t = threadIdx.x;
    #pragma unroll
    for (int i = 0; i < 16; i++) {
        int idx = i * 256 + t;
        int kk = idx >> 6, h = idx & 63;
        tile[h][kk] = f2bf(W[(size_t)(k0 + kk) * HEAD + h]);
    }
    __syncthreads();
    #pragma unroll
    for (int i = 0; i < 16; i++) {
        int idx = i * 256 + t;
        int h = idx >> 6, kk = idx & 63;
        dst[(size_t)h * D_MODEL + k0 + kk] = tile[h][kk];
    }
}

// --- Kernel 1: QKV projection as LDS double-buffered GEMM.
// Computes C^T[g=0..191][m]: A = W rows (192 x K), B = x rows (m x K).
// Grid 512 blocks x 256 thr (4 waves). Block: 32 m-rows, all 192 cols, K=1024
// in 16 steps of 64. Wave w owns h-tiles {3w,3w+1,3w+2} x 2 m-tiles.
// Wt is concatenated [q(64) | k(64) | v(64)] rows x 1024 k (bf16, k-contig).
__global__ __launch_bounds__(256) void qkv_proj(
    const float* __restrict__ x, const u16* __restrict__ Wt,
    u16* __restrict__ qb, u16* __restrict__ kb, u16* __restrict__ vTb)
{
    __shared__ __align__(16) char smem[64512];
    u16* WlB = (u16*)smem;            // [2][192][72]
    u16* XlB = (u16*)(smem + 55296);  // [2][32][72]
    u16* CtB = (u16*)smem;            // epilogue overlay: [32][200]
#define WL(bb,r,c) WlB[((bb)*192 + (r))*72 + (c)]
#define XL(bb,r,c) XlB[((bb)*32  + (r))*72 + (c)]
#define CT(r,c)    CtB[(r)*200 + (c)]

    const int t = threadIdx.x;
    const int wv = t >> 6, lane = t & 63;
    const int ln16 = lane & 15, quad = lane >> 4;
    const int w3 = wv * 3;
    const int m0 = blockIdx.x * 32;

    f32x4 acc[2][3] = {};

    auto stage = [&](int s, int bb) {
        const int k0 = s * 64;
        #pragma unroll
        for (int i = 0; i < 6; i++) {
            int idx = i * 256 + t;
            int row = idx >> 3, cg = (idx & 7) * 8;
            bf16x8 wv8 = ld8(&Wt[(size_t)row * D_MODEL + k0 + cg]);
            *(bf16x8*)&WL(bb, row, cg) = wv8;
        }
        #pragma unroll
        for (int i = 0; i < 2; i++) {
            int idx = i * 256 + t;
            int row = idx >> 4, cs = (idx & 15) * 4;
            const float4 xv = *(const float4*)&x[(size_t)(m0 + row) * D_MODEL + k0 + cs];
            uint2 pk;
            pk.x = (uint32_t)f2bf(xv.x) | ((uint32_t)f2bf(xv.y) << 16);
            pk.y = (uint32_t)f2bf(xv.z) | ((uint32_t)f2bf(xv.w) << 16);
            *(uint2*)&XL(bb, row, cs) = pk;
        }
    };

    stage(0, 0);
    int buf = 0;
    for (int s = 0; s < 16; s++) {
        __syncthreads();
        if (s + 1 < 16) stage(s + 1, buf ^ 1);
        #pragma unroll
        for (int c = 0; c < 2; c++) {
            bf16x8 xb0 = ld8(&XL(buf, ln16,      c * 32 + quad * 8));
            bf16x8 xb1 = ld8(&XL(buf, 16 + ln16, c * 32 + quad * 8));
            #pragma unroll
            for (int j = 0; j < 3; j++) {
                bf16x8 af = ld8(&WL(buf, (w3 + j) * 16 + ln16, c * 32 + quad * 8));
                acc[0][j] = mfma16(af, xb0, acc[0][j]);
                acc[1][j] = mfma16(af, xb1, acc[1][j]);
            }
        }
        buf ^= 1;
    }

    __syncthreads();   // LDS reads done; overlay Ct
    // C/D: col=ln16 = m-local, row=quad*4+r = h-local (within 16-tile)
    #pragma unroll
    for (int mt = 0; mt < 2; mt++) {
        #pragma unroll
        for (int j = 0; j < 3; j++) {
            int g0 = (w3 + j) * 16 + quad * 4;
            float sc = (g0 < 64) ? 0.125f : 1.0f;   // fold softmax scale into q
            uint2 pk;
            pk.x = (uint32_t)f2bf(acc[mt][j][0] * sc) | ((uint32_t)f2bf(acc[mt][j][1] * sc) << 16);
            pk.y = (uint32_t)f2bf(acc[mt][j][2] * sc) | ((uint32_t)f2bf(acc[mt][j][3] * sc) << 16);
            *(uint2*)&CT(mt * 16 + ln16, g0) = pk;
        }
    }
    __syncthreads();
    {   // cooperative coalesced stores
        int m = t >> 3, hg = (t & 7) * 8;
        *(bf16x8*)&qb[(size_t)(m0 + m) * HEAD + hg] = *(bf16x8*)&CT(m, hg);
        *(bf16x8*)&kb[(size_t)(m0 + m) * HEAD + hg] = *(bf16x8*)&CT(m, 64 + hg);
        int h = t >> 2, mg = (t & 3) * 8;
        bf16x8 vv;
        #pragma unroll
        for (int jj = 0; jj < 8; jj++) vv[jj] = (short)CT(mg + jj, 128 + h);
        int bbt = m0 >> 12, l0 = m0 & 4095;
        *(bf16x8*)&vTb[(size_t)(bbt * HEAD + h) * L_SEQ + l0 + mg] = vv;
    }
#undef WL
#undef XL
#undef CT
}

// --- Kernel 2: split-KV causal attention, 2x2 wave split (unchanged from R5).
__global__ __launch_bounds__(256) void attn_chunk(
    const u16* __restrict__ qb, const u16* __restrict__ kb,
    const u16* __restrict__ vT, float* __restrict__ Opart, float* __restrict__ lpart)
{
    const int qt = blockIdx.x, ch = blockIdx.y, b = blockIdx.z;
    if (ch * CHUNK > qt * 64 + 63) return;

    __shared__ __align__(16) char smem[18432];

    const int t = threadIdx.x, wv = t >> 6, lane = t & 63;
    const int ln16 = lane & 15, quad = lane >> 4;
    const int qh = wv & 1, kvh = wv >> 1;
    const int qmin0 = qt * 64 + qh * 32;

    u16 (*P)[72] = (u16(*)[72])smem + wv * 32;
    float (*Cb)[68] = (float(*)[68])smem;
    float* Lb = (float*)(smem + 17408);

    bf16x8 qf[2][2];
    #pragma unroll
    for (int qn = 0; qn < 2; qn++) {
        const u16* qrp = qb + (size_t)(b * L_SEQ + qmin0 + qn * 16 + ln16) * HEAD + quad * 8;
        qf[qn][0] = ld8(qrp); qf[qn][1] = ld8(qrp + 32);
    }

    const u16* kbb = kb + (size_t)b * L_SEQ * HEAD;
    const u16* vbb = vT + (size_t)b * HEAD * L_SEQ;

    f32x4 o[2][4] = {};
    float lsum[2] = {0.f, 0.f};

    const int kv_lo = ch * CHUNK + kvh * (CHUNK / 2);
    const int kv_hi = min(kv_lo + CHUNK / 2, qt * 64 + 64);

    bf16x8 kf0a, kf0b, kf1a, kf1b;
    if (kv_lo < kv_hi) {
        const u16* kr0 = kbb + (size_t)(kv_lo + ln16) * HEAD + quad * 8;
        kf0a = ld8(kr0); kf0b = ld8(kr0 + 32);
        const u16* kr1 = kbb + (size_t)(kv_lo + 16 + ln16) * HEAD + quad * 8;
        kf1a = ld8(kr1); kf1b = ld8(kr1 + 32);
    }

    for (int kv0 = kv_lo; kv0 < kv_hi; kv0 += 64) {
        const u16* kr2 = kbb + (size_t)(kv0 + 32 + ln16) * HEAD + quad * 8;
        bf16x8 kf2a = ld8(kr2), kf2b = ld8(kr2 + 32);
        const u16* kr3 = kbb + (size_t)(kv0 + 48 + ln16) * HEAD + quad * 8;
        bf16x8 kf3a = ld8(kr3), kf3b = ld8(kr3 + 32);
        int kv0n = (kv0 + 64 < kv_hi) ? kv0 + 64 : kv_lo;
        const u16* nr0 = kbb + (size_t)(kv0n + ln16) * HEAD + quad * 8;
        bf16x8 nk0a = ld8(nr0), nk0b = ld8(nr0 + 32);
        const u16* nr1 = kbb + (size_t)(kv0n + 16 + ln16) * HEAD + quad * 8;
        bf16x8 nk1a = ld8(nr1), nk1b = ld8(nr1 + 32);
        const u16* vr0 = vbb + (size_t)ln16 * L_SEQ + kv0 + quad * 8;
        bf16x8 vf0a = ld8(vr0), vf0b = ld8(vr0 + 32);
        const u16* vr1 = vbb + (size_t)(16 + ln16) * L_SEQ + kv0 + quad * 8;
        bf16x8 vf1a = ld8(vr1), vf1b = ld8(vr1 + 32);

        #pragma unroll
        for (int g = 0; g < 4; g++) {
            bf16x8 ka = (g == 0) ? kf0a : (g == 1) ? kf1a : (g == 2) ? kf2a : kf3a;
            bf16x8 kb8 = (g == 0) ? kf0b : (g == 1) ? kf1b : (g == 2) ? kf2b : kf3b;
            #pragma unroll
            for (int qn = 0; qn < 2; qn++) {
                f32x4 s = {};
                s = mfma16(ka, qf[qn][0], s);
                s = mfma16(kb8, qf[qn][1], s);
                float p0, p1, p2, p3;
                if (kv0 + g * 16 + 15 <= qmin0 + qn * 16) {
                    p0 = __expf(s[0]); p1 = __expf(s[1]);
                    p2 = __expf(s[2]); p3 = __expf(s[3]);
                } else {
                    int q = qmin0 + qn * 16 + ln16;
                    int kv = kv0 + g * 16 + quad * 4;
                    p0 = (kv     <= q) ? __expf(s[0]) : 0.f;
                    p1 = (kv + 1 <= q) ? __expf(s[1]) : 0.f;
                    p2 = (kv + 2 <= q) ? __expf(s[2]) : 0.f;
                    p3 = (kv + 3 <= q) ? __expf(s[3]) : 0.f;
                }
                lsum[qn] += p0 + p1 + p2 + p3;
                uint32_t lo = (uint32_t)f2bf(p0) | ((uint32_t)f2bf(p1) << 16);
                uint32_t hi = (uint32_t)f2bf(p2) | ((uint32_t)f2bf(p3) << 16);
                uint32_t* dst = (uint32_t*)&P[qn * 16 + ln16][g * 16 + quad * 4];
                dst[0] = lo; dst[1] = hi;
            }
        }
        bf16x8 pf0[2], pf1[2];
        #pragma unroll
        for (int qn = 0; qn < 2; qn++) {
            pf0[qn] = ld8(&P[qn * 16 + ln16][quad * 8]);
            pf1[qn] = ld8(&P[qn * 16 + ln16][32 + quad * 8]);
        }
        #pragma unroll
        for (int hg = 0; hg < 4; hg++) {
            bf16x8 va, vb2;
            if (hg == 0) { va = vf0a; vb2 = vf0b; }
            else if (hg == 1) { va = vf1a; vb2 = vf1b; }
            else {
                const u16* vr = vbb + (size_t)(hg * 16 + ln16) * L_SEQ + kv0 + quad * 8;
                va = ld8(vr); vb2 = ld8(vr + 32);
            }
            #pragma unroll
            for (int qn = 0; qn < 2; qn++) {
                o[qn][hg] = mfma16(va, pf0[qn], o[qn][hg]);
                o[qn][hg] = mfma16(vb2, pf1[qn], o[qn][hg]);
            }
        }
        kf0a = nk0a; kf0b = nk0b; kf1a = nk1a; kf1b = nk1b;
    }

    #pragma unroll
    for (int qn = 0; qn < 2; qn++) {
        lsum[qn] += __shfl_xor(lsum[qn], 16);
        lsum[qn] += __shfl_xor(lsum[qn], 32);
    }

    __syncthreads();
    if (kvh == 1) {
        #pragma unroll
        for (int qn = 0; qn < 2; qn++) {
            #pragma unroll
            for (int hg = 0; hg < 4; hg++)
                *(f32x4*)&Cb[qh * 32 + qn * 16 + ln16][hg * 16 + quad * 4] = o[qn][hg];
            if (quad == 0) Lb[qh * 32 + qn * 16 + ln16] = lsum[qn];
        }
    }
    __syncthreads();
    if (kvh == 0) {
        const size_t base = (size_t)((b * 64 + qt) * MAXCH + ch);
        #pragma unroll
        for (int qn = 0; qn < 2; qn++) {
            int qrow = qh * 32 + qn * 16 + ln16;
            #pragma unroll
            for (int hg = 0; hg < 4; hg++) {
                f32x4 other = *(f32x4*)&Cb[qrow][hg * 16 + quad * 4];
                f32x4 r = o[qn][hg];
                r[0] += other[0]; r[1] += other[1]; r[2] += other[2]; r[3] += other[3];
                *(f32x4*)&Opart[base * 4096 + (size_t)qrow * 64 + hg * 16 + quad * 4] = r;
            }
            if (quad == 0)
                lpart[base * 64 + qrow] = lsum[qn] + Lb[qrow];
        }
    }
}

// --- Kernel 3: merge partials, float4-wide (max-free: m == 0 everywhere)
__global__ __launch_bounds__(256) void merge_chunks(
    const float* __restrict__ Opart, const float* __restrict__ lpart,
    float* __restrict__ out)
{
    const int qt = blockIdx.x, b = blockIdx.y;
    const int nch = qt / 8 + 1;
    const int t = threadIdx.x;
    const size_t obase = (size_t)((b * 64 + qt) * MAXCH) * 4096;
    const size_t lbase = (size_t)((b * 64 + qt) * MAXCH) * 64;
    #pragma unroll
    for (int i = 0; i < 4; i++) {
        int idx = i * 256 + t;              // 64 q x 16 h-groups
        int q = idx >> 4, hg = (idx & 15) * 4;
        float L = 0.f;
        float ax = 0.f, ay = 0.f, az = 0.f, aw = 0.f;
        for (int c = 0; c < nch; c++) {
            L += lpart[lbase + c * 64 + q];
            const float4 v = *(const float4*)&Opart[obase + (size_t)c * 4096 + q * 64 + hg];
            ax += v.x; ay += v.y; az += v.z; aw += v.w;
        }
        float inv = 1.f / L;
        float4 r; r.x = ax * inv; r.y = ay * inv; r.z = az * inv; r.w = aw * inv;
        *(float4*)&out[((size_t)(b * L_SEQ + qt * 64 + q)) * HEAD + hg] = r;
    }
}

extern "C" void kernel_launch(void* const* d_in, const int* in_sizes, int n_in,
                              void* d_out, int out_size, void* d_ws, size_t ws_size,
                              hipStream_t stream) {
    const float* x  = (const float*)d_in[0];
    const float* Wq = (const float*)d_in[1];
    const float* Wk = (const float*)d_in[2];
    const float* Wv = (const float*)d_in[3];
    float* out = (float*)d_out;

    u16* ws16 = (u16*)d_ws;
    u16* Wt  = ws16;                          // [192][1024] bf16 (q|k|v rows)
    u16* qb  = Wt + 3 * HEAD * D_MODEL;       // [4,4096,64]
    u16* kb  = qb + 16384 * HEAD;
    u16* vTb = kb + 16384 * HEAD;             // [4,64,4096]
    float* Opart = (float*)(vTb + 16384 * HEAD);   // [2048][4096] fp32 = 32 MB
    float* lpart = Opart + (size_t)2048 * 4096;    // [2048][64] fp32

    conv_w      <<<dim3(16, 3), 256, 0, stream>>>(Wq, Wk, Wv, Wt);
    qkv_proj    <<<dim3(512), 256, 0, stream>>>(x, Wt, qb, kb, vTb);
    attn_chunk  <<<dim3(64, 8, 4), 256, 0, stream>>>(qb, kb, vTb, Opart, lpart);
    merge_chunks<<<dim3(64, 4), 256, 0, stream>>>(Opart, lpart, out);
}

// Round 7
// 168.430 us; speedup vs baseline: 2.3664x; 1.0421x over previous
//
#include <hip/hip_runtime.h>
#include <stdint.h>

#define L_SEQ 4096
#define D_MODEL 1024
#define HEAD 64
#define CHUNK 512
#define MAXCH 8
#define NQT 128        // 32-row q tiles

typedef unsigned short u16;
typedef __attribute__((ext_vector_type(8))) short bf16x8;
typedef __attribute__((ext_vector_type(4))) float f32x4;

static __device__ __forceinline__ u16 f2bf(float f) {
    union { float f; uint32_t u; } c; c.f = f;
    uint32_t u = c.u;
    return (u16)((u + 0x7FFFu + ((u >> 16) & 1u)) >> 16);
}
static __device__ __forceinline__ bf16x8 ld8(const u16* p) { return *(const bf16x8*)p; }

static __device__ __forceinline__ f32x4 mfma16(bf16x8 a, bf16x8 b, f32x4 c) {
    return __builtin_amdgcn_mfma_f32_16x16x32_bf16(a, b, c, 0, 0, 0);
}

// --- Kernel 0: W fp32 [1024,64] -> bf16 Wt [64,1024] x3, LDS transpose
__global__ __launch_bounds__(256) void conv_w(
    const float* __restrict__ Wq, const float* __restrict__ Wk,
    const float* __restrict__ Wv, u16* __restrict__ Wt)
{
    __shared__ u16 tile[64][72];
    const float* W = (blockIdx.y == 0) ? Wq : (blockIdx.y == 1) ? Wk : Wv;
    u16* dst = Wt + blockIdx.y * (HEAD * D_MODEL);
    const int k0 = blockIdx.x * 64, t = threadIdx.x;
    #pragma unroll
    for (int i = 0; i < 16; i++) {
        int idx = i * 256 + t;
        int kk = idx >> 6, h = idx & 63;
        tile[h][kk] = f2bf(W[(size_t)(k0 + kk) * HEAD + h]);
    }
    __syncthreads();
    #pragma unroll
    for (int i = 0; i < 16; i++) {
        int idx = i * 256 + t;
        int h = idx >> 6, kk = idx & 63;
        dst[(size_t)h * D_MODEL + k0 + kk] = tile[h][kk];
    }
}

// --- Kernel 1: QKV projection as LDS double-buffered GEMM (unchanged R6).
__global__ __launch_bounds__(256) void qkv_proj(
    const float* __restrict__ x, const u16* __restrict__ Wt,
    u16* __restrict__ qb, u16* __restrict__ kb, u16* __restrict__ vTb)
{
    __shared__ __align__(16) char smem[64512];
    u16* WlB = (u16*)smem;            // [2][192][72]
    u16* XlB = (u16*)(smem + 55296);  // [2][32][72]
    u16* CtB = (u16*)smem;            // epilogue overlay: [32][200]
#define WL(bb,r,c) WlB[((bb)*192 + (r))*72 + (c)]
#define XL(bb,r,c) XlB[((bb)*32  + (r))*72 + (c)]
#define CT(r,c)    CtB[(r)*200 + (c)]

    const int t = threadIdx.x;
    const int wv = t >> 6, lane = t & 63;
    const int ln16 = lane & 15, quad = lane >> 4;
    const int w3 = wv * 3;
    const int m0 = blockIdx.x * 32;

    f32x4 acc[2][3] = {};

    auto stage = [&](int s, int bb) {
        const int k0 = s * 64;
        #pragma unroll
        for (int i = 0; i < 6; i++) {
            int idx = i * 256 + t;
            int row = idx >> 3, cg = (idx & 7) * 8;
            bf16x8 wv8 = ld8(&Wt[(size_t)row * D_MODEL + k0 + cg]);
            *(bf16x8*)&WL(bb, row, cg) = wv8;
        }
        #pragma unroll
        for (int i = 0; i < 2; i++) {
            int idx = i * 256 + t;
            int row = idx >> 4, cs = (idx & 15) * 4;
            const float4 xv = *(const float4*)&x[(size_t)(m0 + row) * D_MODEL + k0 + cs];
            uint2 pk;
            pk.x = (uint32_t)f2bf(xv.x) | ((uint32_t)f2bf(xv.y) << 16);
            pk.y = (uint32_t)f2bf(xv.z) | ((uint32_t)f2bf(xv.w) << 16);
            *(uint2*)&XL(bb, row, cs) = pk;
        }
    };

    stage(0, 0);
    int buf = 0;
    for (int s = 0; s < 16; s++) {
        __syncthreads();
        if (s + 1 < 16) stage(s + 1, buf ^ 1);
        #pragma unroll
        for (int c = 0; c < 2; c++) {
            bf16x8 xb0 = ld8(&XL(buf, ln16,      c * 32 + quad * 8));
            bf16x8 xb1 = ld8(&XL(buf, 16 + ln16, c * 32 + quad * 8));
            #pragma unroll
            for (int j = 0; j < 3; j++) {
                bf16x8 af = ld8(&WL(buf, (w3 + j) * 16 + ln16, c * 32 + quad * 8));
                acc[0][j] = mfma16(af, xb0, acc[0][j]);
                acc[1][j] = mfma16(af, xb1, acc[1][j]);
            }
        }
        buf ^= 1;
    }

    __syncthreads();
    #pragma unroll
    for (int mt = 0; mt < 2; mt++) {
        #pragma unroll
        for (int j = 0; j < 3; j++) {
            int g0 = (w3 + j) * 16 + quad * 4;
            float sc = (g0 < 64) ? 0.125f : 1.0f;
            uint2 pk;
            pk.x = (uint32_t)f2bf(acc[mt][j][0] * sc) | ((uint32_t)f2bf(acc[mt][j][1] * sc) << 16);
            pk.y = (uint32_t)f2bf(acc[mt][j][2] * sc) | ((uint32_t)f2bf(acc[mt][j][3] * sc) << 16);
            *(uint2*)&CT(mt * 16 + ln16, g0) = pk;
        }
    }
    __syncthreads();
    {
        int m = t >> 3, hg = (t & 7) * 8;
        *(bf16x8*)&qb[(size_t)(m0 + m) * HEAD + hg] = *(bf16x8*)&CT(m, hg);
        *(bf16x8*)&kb[(size_t)(m0 + m) * HEAD + hg] = *(bf16x8*)&CT(m, 64 + hg);
        int h = t >> 2, mg = (t & 3) * 8;
        bf16x8 vv;
        #pragma unroll
        for (int jj = 0; jj < 8; jj++) vv[jj] = (short)CT(mg + jj, 128 + h);
        int bbt = m0 >> 12, l0 = m0 & 4095;
        *(bf16x8*)&vTb[(size_t)(bbt * HEAD + h) * L_SEQ + l0 + mg] = vv;
    }
#undef WL
#undef XL
#undef CT
}

// --- Kernel 2: split-KV causal attention, 32-row q-tiles, 4 kv-quarter waves.
// grid (qt=128, ch=8, b=4). Wave = 32 q-rows x <=2 kv-tiles of 64, all loads
// prefetched up front. Cross-wave combine in LDS. launch_bounds(256,2):
// allow ~256 VGPRs so the prefetch set stays in registers.
__global__ __launch_bounds__(256, 2) void attn_chunk(
    const u16* __restrict__ qb, const u16* __restrict__ kb,
    const u16* __restrict__ vT, float* __restrict__ Opart, float* __restrict__ lpart)
{
    const int qt = blockIdx.x, ch = blockIdx.y, b = blockIdx.z;
    if (ch * CHUNK > qt * 32 + 31) return;

    __shared__ __align__(16) char smem[26496]; // loop: P[4][32][72] u16 (18432)
                                               // combine: 3x[32][68] f32 + 3x32 f32

    const int t = threadIdx.x, wv = t >> 6, lane = t & 63;
    const int ln16 = lane & 15, quad = lane >> 4;
    const int qmin0 = qt * 32;

    u16 (*P)[72] = (u16(*)[72])smem + wv * 32;

    // Q as B-operand: B[k=d=quad*8+j][n=q=ln16]; q pre-scaled 1/8
    bf16x8 qf[2][2];
    #pragma unroll
    for (int qn = 0; qn < 2; qn++) {
        const u16* qrp = qb + (size_t)(b * L_SEQ + qmin0 + qn * 16 + ln16) * HEAD + quad * 8;
        qf[qn][0] = ld8(qrp); qf[qn][1] = ld8(qrp + 32);
    }

    const u16* kbb = kb + (size_t)b * L_SEQ * HEAD;
    const u16* vbb = vT + (size_t)b * HEAD * L_SEQ;

    f32x4 o[2][4] = {};          // O^T[h=hg*16+quad*4+r][q=qn*16+ln16]
    float lsum[2] = {0.f, 0.f};

    const int blk_hi = min(ch * CHUNK + CHUNK, qt * 32 + 32);
    const int kv_lo = ch * CHUNK + wv * 128;
    const int kv_hi = min(kv_lo + 128, blk_hi);
    const bool has0 = kv_lo < kv_hi;
    const bool has1 = kv_lo + 64 < kv_hi;

    bf16x8 K0a[4], K0b[4], V0a[4], V0b[4];
    bf16x8 K1a[4], K1b[4], V1a[4], V1b[4];

    if (has0) {
        #pragma unroll
        for (int g = 0; g < 4; g++) {
            const u16* kr = kbb + (size_t)(kv_lo + g * 16 + ln16) * HEAD + quad * 8;
            K0a[g] = ld8(kr); K0b[g] = ld8(kr + 32);
            const u16* vr = vbb + (size_t)(g * 16 + ln16) * L_SEQ + kv_lo + quad * 8;
            V0a[g] = ld8(vr); V0b[g] = ld8(vr + 32);
        }
    }
    if (has1) {
        #pragma unroll
        for (int g = 0; g < 4; g++) {
            const u16* kr = kbb + (size_t)(kv_lo + 64 + g * 16 + ln16) * HEAD + quad * 8;
            K1a[g] = ld8(kr); K1b[g] = ld8(kr + 32);
            const u16* vr = vbb + (size_t)(g * 16 + ln16) * L_SEQ + kv_lo + 64 + quad * 8;
            V1a[g] = ld8(vr); V1b[g] = ld8(vr + 32);
        }
    }

    auto tile = [&](int kv0, bf16x8* Ka, bf16x8* Kb2, bf16x8* Va, bf16x8* Vb2) {
        #pragma unroll
        for (int g = 0; g < 4; g++) {
            #pragma unroll
            for (int qn = 0; qn < 2; qn++) {
                f32x4 s = {};
                s = mfma16(Ka[g], qf[qn][0], s);
                s = mfma16(Kb2[g], qf[qn][1], s);
                // S^T[kv=kv0+g*16+quad*4+r][q=qmin0+qn*16+ln16]
                float p0, p1, p2, p3;
                if (kv0 + g * 16 + 15 <= qmin0 + qn * 16) {   // fully unmasked
                    p0 = __expf(s[0]); p1 = __expf(s[1]);
                    p2 = __expf(s[2]); p3 = __expf(s[3]);
                } else {
                    int q = qmin0 + qn * 16 + ln16;
                    int kv = kv0 + g * 16 + quad * 4;
                    p0 = (kv     <= q) ? __expf(s[0]) : 0.f;
                    p1 = (kv + 1 <= q) ? __expf(s[1]) : 0.f;
                    p2 = (kv + 2 <= q) ? __expf(s[2]) : 0.f;
                    p3 = (kv + 3 <= q) ? __expf(s[3]) : 0.f;
                }
                lsum[qn] += p0 + p1 + p2 + p3;
                uint32_t lo = (uint32_t)f2bf(p0) | ((uint32_t)f2bf(p1) << 16);
                uint32_t hi = (uint32_t)f2bf(p2) | ((uint32_t)f2bf(p3) << 16);
                uint32_t* dst = (uint32_t*)&P[qn * 16 + ln16][g * 16 + quad * 4];
                dst[0] = lo; dst[1] = hi;
            }
        }
        bf16x8 pf0[2], pf1[2];
        #pragma unroll
        for (int qn = 0; qn < 2; qn++) {
            pf0[qn] = ld8(&P[qn * 16 + ln16][quad * 8]);       // same-wave, ordered
            pf1[qn] = ld8(&P[qn * 16 + ln16][32 + quad * 8]);
        }
        #pragma unroll
        for (int hg = 0; hg < 4; hg++) {
            #pragma unroll
            for (int qn = 0; qn < 2; qn++) {
                o[qn][hg] = mfma16(Va[hg], pf0[qn], o[qn][hg]);
                o[qn][hg] = mfma16(Vb2[hg], pf1[qn], o[qn][hg]);
            }
        }
    };

    if (has0) tile(kv_lo,      K0a, K0b, V0a, V0b);
    if (has1) tile(kv_lo + 64, K1a, K1b, V1a, V1b);

    #pragma unroll
    for (int qn = 0; qn < 2; qn++) {
        lsum[qn] += __shfl_xor(lsum[qn], 16);
        lsum[qn] += __shfl_xor(lsum[qn], 32);
    }

    // --- cross-wave combine (4 kv-quarters) ---
    __syncthreads();                 // P dead; smem becomes cbuf/lbuf
    float (*cb)[68] = (float(*)[68])smem;
    float* lb = (float*)(smem + 26112);
    if (wv > 0) {
        #pragma unroll
        for (int qn = 0; qn < 2; qn++) {
            #pragma unroll
            for (int hg = 0; hg < 4; hg++)
                *(f32x4*)&cb[(wv - 1) * 32 + qn * 16 + ln16][hg * 16 + quad * 4] = o[qn][hg];
            if (quad == 0) lb[(wv - 1) * 32 + qn * 16 + ln16] = lsum[qn];
        }
    }
    __syncthreads();
    if (wv == 0) {
        const size_t base = (size_t)((b * NQT + qt) * MAXCH + ch);
        #pragma unroll
        for (int qn = 0; qn < 2; qn++) {
            int q = qn * 16 + ln16;
            #pragma unroll
            for (int w2 = 0; w2 < 3; w2++) {
                lsum[qn] += lb[w2 * 32 + q];
                #pragma unroll
                for (int hg = 0; hg < 4; hg++) {
                    f32x4 v = *(f32x4*)&cb[w2 * 32 + q][hg * 16 + quad * 4];
                    o[qn][hg][0] += v[0]; o[qn][hg][1] += v[1];
                    o[qn][hg][2] += v[2]; o[qn][hg][3] += v[3];
                }
            }
            #pragma unroll
            for (int hg = 0; hg < 4; hg++)
                *(f32x4*)&Opart[base * 2048 + (size_t)q * 64 + hg * 16 + quad * 4] = o[qn][hg];
            if (quad == 0)
                lpart[base * 32 + q] = lsum[qn];
        }
    }
}

// --- Kernel 3: merge partials; unrolled independent loads (poison-safe x0).
__global__ __launch_bounds__(256) void merge_chunks(
    const float* __restrict__ Opart, const float* __restrict__ lpart,
    float* __restrict__ out)
{
    const int qt = blockIdx.x, b = blockIdx.y;
    const int nch = qt / 16 + 1;
    const int t = threadIdx.x;
    const size_t obase = (size_t)((b * NQT + qt) * MAXCH) * 2048;
    const size_t lbase = (size_t)((b * NQT + qt) * MAXCH) * 32;
    #pragma unroll
    for (int i = 0; i < 2; i++) {
        int idx = i * 256 + t;              // 32 q x 16 h-groups
        int q = idx >> 4, hg = (idx & 15) * 4;
        f32x4 vals[MAXCH];
        float ls[MAXCH];
        #pragma unroll
        for (int c = 0; c < MAXCH; c++) {   // unconditional: 8 independent loads
            vals[c] = *(const f32x4*)&Opart[obase + (size_t)c * 2048 + q * 64 + hg];
            ls[c] = lpart[lbase + c * 32 + q];
        }
        float L = 0.f, ax = 0.f, ay = 0.f, az = 0.f, aw = 0.f;
        #pragma unroll
        for (int c = 0; c < MAXCH; c++) {
            float m = (c < nch) ? 1.f : 0.f;
            L += ls[c] * m;
            ax += vals[c][0] * m; ay += vals[c][1] * m;
            az += vals[c][2] * m; aw += vals[c][3] * m;
        }
        float inv = 1.f / L;
        float4 r; r.x = ax * inv; r.y = ay * inv; r.z = az * inv; r.w = aw * inv;
        *(float4*)&out[((size_t)(b * L_SEQ + qt * 32 + q)) * HEAD + hg] = r;
    }
}

extern "C" void kernel_launch(void* const* d_in, const int* in_sizes, int n_in,
                              void* d_out, int out_size, void* d_ws, size_t ws_size,
                              hipStream_t stream) {
    const float* x  = (const float*)d_in[0];
    const float* Wq = (const float*)d_in[1];
    const float* Wk = (const float*)d_in[2];
    const float* Wv = (const float*)d_in[3];
    float* out = (float*)d_out;

    u16* ws16 = (u16*)d_ws;
    u16* Wt  = ws16;                          // [192][1024] bf16 (q|k|v rows)
    u16* qb  = Wt + 3 * HEAD * D_MODEL;       // [4,4096,64]
    u16* kb  = qb + 16384 * HEAD;
    u16* vTb = kb + 16384 * HEAD;             // [4,64,4096]
    float* Opart = (float*)(vTb + 16384 * HEAD);   // [4096][2048] fp32 = 33.5 MB
    float* lpart = Opart + (size_t)4096 * 2048;    // [4096][32] fp32

    conv_w      <<<dim3(16, 3), 256, 0, stream>>>(Wq, Wk, Wv, Wt);
    qkv_proj    <<<dim3(512), 256, 0, stream>>>(x, Wt, qb, kb, vTb);
    attn_chunk  <<<dim3(NQT, 8, 4), 256, 0, stream>>>(qb, kb, vTb, Opart, lpart);
    merge_chunks<<<dim3(NQT, 4), 256, 0, stream>>>(Opart, lpart, out);
}

// Round 8
// 163.351 us; speedup vs baseline: 2.4400x; 1.0311x over previous
//
#include <hip/hip_runtime.h>
#include <stdint.h>

#define L_SEQ 4096
#define D_MODEL 1024
#define HEAD 64
#define CHUNK 512
#define MAXCH 8
#define NQT 32          // 128-row q tiles

typedef unsigned short u16;
typedef __attribute__((ext_vector_type(8))) short bf16x8;
typedef __attribute__((ext_vector_type(4))) float f32x4;

static __device__ __forceinline__ u16 f2bf(float f) {
    union { float f; uint32_t u; } c; c.f = f;
    uint32_t u = c.u;
    return (u16)((u + 0x7FFFu + ((u >> 16) & 1u)) >> 16);
}
static __device__ __forceinline__ bf16x8 ld8(const u16* p) { return *(const bf16x8*)p; }

static __device__ __forceinline__ f32x4 mfma16(bf16x8 a, bf16x8 b, f32x4 c) {
    return __builtin_amdgcn_mfma_f32_16x16x32_bf16(a, b, c, 0, 0, 0);
}

// async global->LDS, 16B per lane, fire-and-forget (cannot be sunk by compiler)
static __device__ __forceinline__ void gload16(const u16* g, u16* l) {
    __builtin_amdgcn_global_load_lds(
        (const __attribute__((address_space(1))) void*)g,
        (__attribute__((address_space(3))) void*)l, 16, 0, 0);
}

// --- Kernel 0: W fp32 [1024,64] -> bf16 Wt [64,1024] x3, LDS transpose
__global__ __launch_bounds__(256) void conv_w(
    const float* __restrict__ Wq, const float* __restrict__ Wk,
    const float* __restrict__ Wv, u16* __restrict__ Wt)
{
    __shared__ u16 tile[64][72];
    const float* W = (blockIdx.y == 0) ? Wq : (blockIdx.y == 1) ? Wk : Wv;
    u16* dst = Wt + blockIdx.y * (HEAD * D_MODEL);
    const int k0 = blockIdx.x * 64, t = threadIdx.x;
    #pragma unroll
    for (int i = 0; i < 16; i++) {
        int idx = i * 256 + t;
        int kk = idx >> 6, h = idx & 63;
        tile[h][kk] = f2bf(W[(size_t)(k0 + kk) * HEAD + h]);
    }
    __syncthreads();
    #pragma unroll
    for (int i = 0; i < 16; i++) {
        int idx = i * 256 + t;
        int h = idx >> 6, kk = idx & 63;
        dst[(size_t)h * D_MODEL + k0 + kk] = tile[h][kk];
    }
}

// --- Kernel 1: QKV projection, W staged via global_load_lds (async), dbuf.
// W LDS layout [buf][dhalf][192][32] (64B rows -> 2-way bank alias = free).
// x fp32 -> regs -> bf16 pack -> LDS [buf][khalf][32][36] (padded ok).
__global__ __launch_bounds__(256) void qkv_proj(
    const float* __restrict__ x, const u16* __restrict__ Wt,
    u16* __restrict__ qb, u16* __restrict__ kb, u16* __restrict__ vTb)
{
    __shared__ __align__(16) u16 Wl[2 * 2 * 192 * 32];   // 49152 B
    __shared__ __align__(16) u16 Xl[2 * 2 * 32 * 36];    // 9216 B
#define WLX(bb,dh,r,c) Wl[(((bb)*2 + (dh))*192 + (r))*32 + (c)]
#define XLX(bb,kh,r,c) Xl[(((bb)*2 + (kh))*32  + (r))*36 + (c)]
#define CT(r,c)        ((u16*)Wl)[(r)*200 + (c)]        // epilogue overlay

    const int t = threadIdx.x;
    const int wv = t >> 6, lane = t & 63;
    const int ln16 = lane & 15, quad = lane >> 4;
    const int w3 = wv * 3;
    const int m0 = blockIdx.x * 32;

    f32x4 acc[2][3] = {};
    float4 xv0, xv1;

    auto issueW = [&](int s, int bb) {
        const int k0 = s * 64;
        #pragma unroll
        for (int k2 = 0; k2 < 6; k2++) {
            int c = wv * 6 + k2;
            int dh = c & 1, g = c >> 1;
            const u16* gp = Wt + (size_t)(g * 16 + (lane >> 2)) * D_MODEL
                               + k0 + dh * 32 + (lane & 3) * 8;
            gload16(gp, &WLX(bb, dh, g * 16 + (lane >> 2), (lane & 3) * 8));
        }
    };
    auto loadx = [&](int s) {
        const int k0 = s * 64;
        int r0 = t >> 4, cs0 = (t & 15) * 4;
        xv0 = *(const float4*)&x[(size_t)(m0 + r0) * D_MODEL + k0 + cs0];
        int idx = 256 + t, r1 = idx >> 4, cs1 = (idx & 15) * 4;
        xv1 = *(const float4*)&x[(size_t)(m0 + r1) * D_MODEL + k0 + cs1];
    };
    auto packx = [&](int bb) {
        int r0 = t >> 4, cs0 = (t & 15) * 4;
        uint2 p0;
        p0.x = (uint32_t)f2bf(xv0.x) | ((uint32_t)f2bf(xv0.y) << 16);
        p0.y = (uint32_t)f2bf(xv0.z) | ((uint32_t)f2bf(xv0.w) << 16);
        *(uint2*)&XLX(bb, cs0 >> 5, r0, cs0 & 31) = p0;
        int idx = 256 + t, r1 = idx >> 4, cs1 = (idx & 15) * 4;
        uint2 p1;
        p1.x = (uint32_t)f2bf(xv1.x) | ((uint32_t)f2bf(xv1.y) << 16);
        p1.y = (uint32_t)f2bf(xv1.z) | ((uint32_t)f2bf(xv1.w) << 16);
        *(uint2*)&XLX(bb, cs1 >> 5, r1, cs1 & 31) = p1;
    };

    issueW(0, 0);
    loadx(0);
    packx(0);
    int buf = 0;
    for (int s = 0; s < 16; s++) {
        __syncthreads();
        if (s + 1 < 16) { issueW(s + 1, buf ^ 1); loadx(s + 1); }
        #pragma unroll
        for (int c = 0; c < 2; c++) {
            bf16x8 xb0 = ld8(&XLX(buf, c, ln16, quad * 8));
            bf16x8 xb1 = ld8(&XLX(buf, c, 16 + ln16, quad * 8));
            #pragma unroll
            for (int j = 0; j < 3; j++) {
                bf16x8 af = ld8(&WLX(buf, c, (w3 + j) * 16 + ln16, quad * 8));
                acc[0][j] = mfma16(af, xb0, acc[0][j]);
                acc[1][j] = mfma16(af, xb1, acc[1][j]);
            }
        }
        if (s + 1 < 16) packx(buf ^ 1);
        buf ^= 1;
    }

    __syncthreads();   // staging done; overlay Ct on W region
    #pragma unroll
    for (int mt = 0; mt < 2; mt++) {
        #pragma unroll
        for (int j = 0; j < 3; j++) {
            int g0 = (w3 + j) * 16 + quad * 4;
            float sc = (g0 < 64) ? 0.125f : 1.0f;    // fold softmax scale into q
            uint2 pk;
            pk.x = (uint32_t)f2bf(acc[mt][j][0] * sc) | ((uint32_t)f2bf(acc[mt][j][1] * sc) << 16);
            pk.y = (uint32_t)f2bf(acc[mt][j][2] * sc) | ((uint32_t)f2bf(acc[mt][j][3] * sc) << 16);
            *(uint2*)&CT(mt * 16 + ln16, g0) = pk;
        }
    }
    __syncthreads();
    {
        int m = t >> 3, hg = (t & 7) * 8;
        *(bf16x8*)&qb[(size_t)(m0 + m) * HEAD + hg] = *(bf16x8*)&CT(m, hg);
        *(bf16x8*)&kb[(size_t)(m0 + m) * HEAD + hg] = *(bf16x8*)&CT(m, 64 + hg);
        int h = t >> 2, mg = (t & 3) * 8;
        bf16x8 vvv;
        #pragma unroll
        for (int jj = 0; jj < 8; jj++) vvv[jj] = (short)CT(mg + jj, 128 + h);
        int bbt = m0 >> 12, l0 = m0 & 4095;
        *(bf16x8*)&vTb[(size_t)(bbt * HEAD + h) * L_SEQ + l0 + mg] = vvv;
    }
#undef WLX
#undef XLX
#undef CT
}

// --- Kernel 2: split-KV causal attention, m97-style async LDS pipeline.
// grid (qt=32 [128 q-rows], ch=8, b=4). Block = 4 waves x 32 q-rows each.
// Per 64-kv stage: K,V staged via global_load_lds into [dhalf/kvhalf][64][32]
// (64B rows, no padding needed), double-buffered, 1 barrier/stage.
__global__ __launch_bounds__(256) void attn_chunk(
    const u16* __restrict__ qb, const u16* __restrict__ kb,
    const u16* __restrict__ vT, float* __restrict__ Opart, float* __restrict__ lpart)
{
    const int qt = blockIdx.x, ch = blockIdx.y, b = blockIdx.z;
    if (ch * CHUNK > qt * 128 + 127) return;

    __shared__ __align__(16) u16 Kls[2 * 2 * 64 * 32];   // 16 KB
    __shared__ __align__(16) u16 Vls[2 * 2 * 64 * 32];   // 16 KB
    __shared__ __align__(16) u16 Pls[4 * 32 * 72];       // 18 KB, wave-private P
#define KBX(bb,dh,r,c) Kls[(((bb)*2 + (dh))*64 + (r))*32 + (c)]
#define VBX(bb,kh,r,c) Vls[(((bb)*2 + (kh))*64 + (r))*32 + (c)]
#define PX(r,c)        Pls[((wv)*32 + (r))*72 + (c)]

    const int t = threadIdx.x, wv = t >> 6, lane = t & 63;
    const int ln16 = lane & 15, quad = lane >> 4;
    const int qmin = qt * 128 + wv * 32;    // wave's lowest q row

    // Q as B-operand: B[k=d=quad*8+j][n=q=ln16]; q pre-scaled 1/8
    bf16x8 qf[2][2];
    #pragma unroll
    for (int qn = 0; qn < 2; qn++) {
        const u16* qrp = qb + (size_t)(b * L_SEQ + qmin + qn * 16 + ln16) * HEAD + quad * 8;
        qf[qn][0] = ld8(qrp); qf[qn][1] = ld8(qrp + 32);
    }

    const u16* kbb = kb + (size_t)b * L_SEQ * HEAD;
    const u16* vbb = vT + (size_t)b * HEAD * L_SEQ;

    f32x4 o[2][4] = {};            // O^T[h=hg*16+quad*4+r][q=qn*16+ln16]
    float lsum[2] = {0.f, 0.f};

    const int kv_lo = ch * CHUNK;
    const int kv_hi = min(kv_lo + CHUNK, qt * 128 + 128);
    const int nst = (kv_hi - kv_lo) >> 6;

    // 16 chunks of 1024B per stage: c<8 -> K(dhalf=c&1, g=c>>1); else V.
    auto issue_stage = [&](int kv0, int bb) {
        #pragma unroll
        for (int k2 = 0; k2 < 4; k2++) {
            int c = wv * 4 + k2;
            if (c < 8) {
                int dh = c & 1, g = c >> 1;
                const u16* gp = kbb + (size_t)(kv0 + g * 16 + (lane >> 2)) * HEAD
                                    + dh * 32 + (lane & 3) * 8;
                gload16(gp, &KBX(bb, dh, g * 16 + (lane >> 2), (lane & 3) * 8));
            } else {
                int c2 = c - 8, kh = c2 & 1, g = c2 >> 1;
                const u16* gp = vbb + (size_t)(g * 16 + (lane >> 2)) * L_SEQ
                                    + kv0 + kh * 32 + (lane & 3) * 8;
                gload16(gp, &VBX(bb, kh, g * 16 + (lane >> 2), (lane & 3) * 8));
            }
        }
    };

    issue_stage(kv_lo, 0);
    int buf = 0;
    for (int s = 0; s < nst; s++) {
        __syncthreads();                              // drains stage(s) loads
        if (s + 1 < nst) issue_stage(kv_lo + (s + 1) * 64, buf ^ 1);
        const int kv0 = kv_lo + s * 64;

        // S^T = K Q^T: A = K rows from LDS, frags reused across qn
        #pragma unroll
        for (int g = 0; g < 4; g++) {
            bf16x8 ka0 = ld8(&KBX(buf, 0, g * 16 + ln16, quad * 8));
            bf16x8 ka1 = ld8(&KBX(buf, 1, g * 16 + ln16, quad * 8));
            #pragma unroll
            for (int qn = 0; qn < 2; qn++) {
                f32x4 s2 = {};
                s2 = mfma16(ka0, qf[qn][0], s2);
                s2 = mfma16(ka1, qf[qn][1], s2);
                // S^T[kv=kv0+g*16+quad*4+r][q=qmin+qn*16+ln16]
                float p0, p1, p2, p3;
                if (kv0 + g * 16 + 15 <= qmin + qn * 16) {     // fully unmasked
                    p0 = __expf(s2[0]); p1 = __expf(s2[1]);
                    p2 = __expf(s2[2]); p3 = __expf(s2[3]);
                } else {
                    int q = qmin + qn * 16 + ln16;
                    int kv = kv0 + g * 16 + quad * 4;
                    p0 = (kv     <= q) ? __expf(s2[0]) : 0.f;
                    p1 = (kv + 1 <= q) ? __expf(s2[1]) : 0.f;
                    p2 = (kv + 2 <= q) ? __expf(s2[2]) : 0.f;
                    p3 = (kv + 3 <= q) ? __expf(s2[3]) : 0.f;
                }
                lsum[qn] += p0 + p1 + p2 + p3;
                uint2 pk;
                pk.x = (uint32_t)f2bf(p0) | ((uint32_t)f2bf(p1) << 16);
                pk.y = (uint32_t)f2bf(p2) | ((uint32_t)f2bf(p3) << 16);
                *(uint2*)&PX(qn * 16 + ln16, g * 16 + quad * 4) = pk;
            }
        }
        // P back as B-operand (same-wave LDS, ordered)
        bf16x8 pf[2][2];
        #pragma unroll
        for (int qn = 0; qn < 2; qn++) {
            pf[qn][0] = ld8(&PX(qn * 16 + ln16, quad * 8));
            pf[qn][1] = ld8(&PX(qn * 16 + ln16, 32 + quad * 8));
        }
        // O^T += V^T P^T: A = V^T rows from LDS, frags reused across qn
        #pragma unroll
        for (int hg = 0; hg < 4; hg++) {
            bf16x8 va0 = ld8(&VBX(buf, 0, hg * 16 + ln16, quad * 8));
            bf16x8 va1 = ld8(&VBX(buf, 1, hg * 16 + ln16, quad * 8));
            #pragma unroll
            for (int qn = 0; qn < 2; qn++) {
                o[qn][hg] = mfma16(va0, pf[qn][0], o[qn][hg]);
                o[qn][hg] = mfma16(va1, pf[qn][1], o[qn][hg]);
            }
        }
        buf ^= 1;
    }

    #pragma unroll
    for (int qn = 0; qn < 2; qn++) {
        lsum[qn] += __shfl_xor(lsum[qn], 16);
        lsum[qn] += __shfl_xor(lsum[qn], 32);
    }

    // each wave owns its 32 q rows: store partials directly, no combine
    const size_t base = (size_t)((b * NQT + qt) * MAXCH + ch);
    #pragma unroll
    for (int qn = 0; qn < 2; qn++) {
        int q_local = wv * 32 + qn * 16 + ln16;
        #pragma unroll
        for (int hg = 0; hg < 4; hg++)
            *(f32x4*)&Opart[base * 8192 + (size_t)q_local * 64 + hg * 16 + quad * 4] = o[qn][hg];
        if (quad == 0)
            lpart[base * 128 + q_local] = lsum[qn];
    }
#undef KBX
#undef VBX
#undef PX
}

// --- Kernel 3: merge partials; unconditional unrolled loads (poison x0 safe).
__global__ __launch_bounds__(256) void merge_chunks(
    const float* __restrict__ Opart, const float* __restrict__ lpart,
    float* __restrict__ out)
{
    const int qt = blockIdx.x, b = blockIdx.y;
    const int nch = qt / 4 + 1;
    const int t = threadIdx.x;
    const size_t obase = (size_t)((b * NQT + qt) * MAXCH) * 8192;
    const size_t lbase = (size_t)((b * NQT + qt) * MAXCH) * 128;
    #pragma unroll
    for (int i = 0; i < 8; i++) {
        int idx = i * 256 + t;              // 128 q x 16 h-groups
        int q = idx >> 4, hg = (idx & 15) * 4;
        f32x4 vals[MAXCH];
        float ls[MAXCH];
        #pragma unroll
        for (int c = 0; c < MAXCH; c++) {
            vals[c] = *(const f32x4*)&Opart[obase + (size_t)c * 8192 + q * 64 + hg];
            ls[c] = lpart[lbase + c * 128 + q];
        }
        float L = 0.f, ax = 0.f, ay = 0.f, az = 0.f, aw = 0.f;
        #pragma unroll
        for (int c = 0; c < MAXCH; c++) {
            float m = (c < nch) ? 1.f : 0.f;
            L += ls[c] * m;
            ax += vals[c][0] * m; ay += vals[c][1] * m;
            az += vals[c][2] * m; aw += vals[c][3] * m;
        }
        float inv = 1.f / L;
        float4 r; r.x = ax * inv; r.y = ay * inv; r.z = az * inv; r.w = aw * inv;
        *(float4*)&out[((size_t)(b * L_SEQ + qt * 128 + q)) * HEAD + hg] = r;
    }
}

extern "C" void kernel_launch(void* const* d_in, const int* in_sizes, int n_in,
                              void* d_out, int out_size, void* d_ws, size_t ws_size,
                              hipStream_t stream) {
    const float* x  = (const float*)d_in[0];
    const float* Wq = (const float*)d_in[1];
    const float* Wk = (const float*)d_in[2];
    const float* Wv = (const float*)d_in[3];
    float* out = (float*)d_out;

    u16* ws16 = (u16*)d_ws;
    u16* Wt  = ws16;                          // [192][1024] bf16 (q|k|v rows)
    u16* qb  = Wt + 3 * HEAD * D_MODEL;       // [4,4096,64]
    u16* kb  = qb + 16384 * HEAD;
    u16* vTb = kb + 16384 * HEAD;             // [4,64,4096]
    float* Opart = (float*)(vTb + 16384 * HEAD);   // [4*32*8][8192] f32 = 33.5 MB
    float* lpart = Opart + (size_t)1024 * 8192;    // [4*32*8][128] f32

    conv_w      <<<dim3(16, 3), 256, 0, stream>>>(Wq, Wk, Wv, Wt);
    qkv_proj    <<<dim3(512), 256, 0, stream>>>(x, Wt, qb, kb, vTb);
    attn_chunk  <<<dim3(NQT, 8, 4), 256, 0, stream>>>(qb, kb, vTb, Opart, lpart);
    merge_chunks<<<dim3(NQT, 4), 256, 0, stream>>>(Opart, lpart, out);
}